// Round 10
// baseline (372.611 us; speedup 1.0000x reference)
//
#include <hip/hip_runtime.h>
#include <cstdint>
#include <cstddef>

// IT_Fast_Attn: B=8, C=256, N=4096, 2 iterations. fp32 I/O, bf16 compute.
// Round 19 = r18 resubmit (r9 bench was an infra failure: container died
// twice, no measurement). r18 content, re-audited:
//   - sxb_k (once): SXb = exp(Xb)/rowsum, vstat[row]={sum,sumsq} of Xb.
//   - OUT gemms: TRF 1->0 (glds path), MODE 6: store + per-row {sum,sumsq}
//     -> omstat via shuffle+sparse atomics (r17's proven pattern).
//   - MLP gemm MODE 7 = MODE3 + omstat accumulation.
//   - ln256t(it0) direct-stores vstat for Vb (full-row blocks, no atomics).
//   - res gemm MODE4 computes mean/rstd inline from vstat+omstat.
//   - omstat zeroed inside ctxreduce_k; stats1024_k deleted.
//   r16 lesson respected: ~0.8M SPREAD atomics off the data path.
// Swizzle (rule #21 both-sides): global chunk (t&7)^(sRow&7), read chunk
// (h*4+q)^(mrow&7); phys chunk p of row r = logical p^(r&7).

using u16 = unsigned short;
using short8 = __attribute__((ext_vector_type(8))) short;
using bf16x8 = __attribute__((ext_vector_type(8))) __bf16;
using f32x4  = __attribute__((ext_vector_type(4))) float;
using i32x4  = __attribute__((ext_vector_type(4))) int;
using u16x4  = __attribute__((ext_vector_type(4))) u16;
using u16x8  = __attribute__((ext_vector_type(8))) u16;

__device__ __forceinline__ float b2f(u16 u) {
    union { unsigned u32; float f; } c; c.u32 = ((unsigned)u) << 16; return c.f;
}
__device__ __forceinline__ u16 f2b(float f) {
    union { float f; unsigned u; } c; c.f = f;
    unsigned r = c.u + 0x7FFFu + ((c.u >> 16) & 1u);
    return (u16)(r >> 16);
}
__device__ __forceinline__ void cvt(u16 a,  u16& o)   { o = a; }
__device__ __forceinline__ void cvt(float a, u16& o)  { o = f2b(a); }
__device__ __forceinline__ void cvt(float a, float& o){ o = a; }
__device__ __forceinline__ void cvt(u16 a,  float& o) { o = b2f(a); }

// async global->LDS, 16 B/lane; lds dest = wave-uniform base + lane*16.
__device__ __forceinline__ void glds16(const u16* g, short* l) {
    __builtin_amdgcn_global_load_lds(
        (const __attribute__((address_space(1))) void*)g,
        (__attribute__((address_space(3))) void*)l, 16, 0, 0);
}

// ---------------------------------------------------------------------------
// BT GEMM: C[row,col] = sum_k A[row,k] * B[col,k].  BM=BN=128, BK=64.
// 512 threads = 8 waves in 4x2; wave covers 32 rows x 64 cols; 16 MFMAs/iter
// (2 mi x 4 ni x 2 k-halves of 16x16x32 bf16). COL-fastest grid (L2 A-reuse).
// Staging: wave w DMAs rows [w*8, w*8+8) of each 64-row half via
// global_load_lds (lane l -> row w*8+(l>>3), phys chunk l&7, global chunk
// (l&7)^((l>>3)&7)).  LDS stride 64 shorts, XOR-swizzled chunks.
// TRF: 0 plain | 1 softmax exp(a-st.x)*st.y (A reg-staged; UNUSED now) |
//      2 three-source region split over A|A2|A3 | 3 two-source split.
// MODE: 0 store bf16 | 1 fp32 partial per ks-slice | 3 +bias,relu,bf16
//       | 4 LN-fold epilogue, stats from vstat(stats)+omstat(bias)
//       | 5 fused qkv: Xb + XT(Xres) + per-row exp-sum atomics (stats.y)
//       | 6 store bf16 + omstat(stats) {sum,sumsq} atomics
//       | 7 = MODE3 + omstat(stats) atomics.
// ---------------------------------------------------------------------------
template<int MODE, int TRF>
__global__ __launch_bounds__(512)
void gemm_bt(const u16* __restrict__ A, const u16* __restrict__ A2,
             const u16* __restrict__ A3,
             int lda, int lda2, int lda3, int kSplit,
             const u16* __restrict__ B, int ldb, long strA, long strB,
             int statStride, int kChunk, int nKsplit,
             float* __restrict__ outF, u16* __restrict__ outB,
             long sOF, long sOB, int ldo,
             const u16* __restrict__ Xres,
             const float* __restrict__ bias,
             const float2* __restrict__ stats,
             const float* __restrict__ g, const float* __restrict__ be)
{
    __shared__ short lsA[128 * 64];
    __shared__ short lsB[128 * 64];

    const int bz    = blockIdx.z;
    const int batch = bz / nKsplit;
    const int ks    = bz - batch * nKsplit;
    const u16* Ab = A + (size_t)batch * strA;
    const u16* Bb = B + (size_t)batch * strB;
    const int colBase = blockIdx.x * 128;   // col-fastest
    const int rowBase = blockIdx.y * 128;
    const int k0 = ks * kChunk;
    const int k1 = k0 + kChunk;

    const int t    = threadIdx.x;
    const int sRow = t >> 3;                         // 0..63
    const int sKl  = (t & 7) << 3;                   // linear lds chunk (elems)
    const int sKg  = (((t & 7) ^ (sRow & 7)) << 3);  // swizzled global chunk

    const int lane = t & 63;
    const int w    = t >> 6;           // 0..7
    const int wr   = (w >> 1) * 32;    // wave row base
    const int wc   = (w & 1) * 64;     // wave col base
    const int mrow = lane & 15;
    const int q    = lane >> 4;

    // wave-uniform LDS DMA destinations (rows w*8..w*8+7 of each half)
    short* ldA0 = &lsA[w * 512];
    short* ldA1 = &lsA[4096 + w * 512];
    short* ldB0 = &lsB[w * 512];
    short* ldB1 = &lsB[4096 + w * 512];

    float2 st0 = {0.f, 0.f}, st1 = {0.f, 0.f};
    if (TRF == 1) {
        const int sb = batch * statStride + rowBase;
        const float2 t0 = stats[sb + sRow];
        const float2 t1 = stats[sb + sRow + 64];
        st0 = make_float2(0.f, 1.f / t0.y);
        st1 = make_float2(0.f, 1.f / t1.y);
    }

    // per-lane global A pointer for window base kn (region from kn; the
    // swizzled chunk sKg stays inside [kn, kn+64))
    auto aPtr = [&](int rloc, int kn) -> const u16* {
        const int arow = rowBase + rloc + sRow;
        if (TRF == 2) {
            if (kn < 256)      return A  + (size_t)arow * lda  + kn + sKg;
            else if (kn < 512) return A2 + (size_t)arow * lda2 + (kn - 256) + sKg;
            else               return A3 + (size_t)arow * lda3 + (kn - 512) + sKg;
        } else if (TRF == 3) {
            if (kn < kSplit)   return Ab + (size_t)arow * lda + kn + sKg;
            return A2 + (size_t)arow * lda2 + (kn - kSplit) + sKg;
        }
        return Ab + (size_t)arow * lda + kn + sKg;
    };
    // TRF==1 reg path (unused in current call set; kept for completeness)
    auto loadX = [&](int rloc, int kn, float2 st) -> i32x4 {
        const int arow = rowBase + rloc + sRow;
        i32x4 raw = *(const i32x4*)(Ab + (size_t)arow * lda + kn + sKg);
        short8 h = __builtin_bit_cast(short8, raw);
        short8 o;
#pragma unroll
        for (int i = 0; i < 8; i++) {
            float v = b2f((u16)h[i]);
            v = __expf(v - st.x) * st.y;
            o[i] = (short)f2b(v);
        }
        return __builtin_bit_cast(i32x4, o);
    };

    const f32x4 fzero = {0.f, 0.f, 0.f, 0.f};
    f32x4 acc[2][4];
#pragma unroll
    for (int i = 0; i < 2; i++)
#pragma unroll
        for (int j = 0; j < 4; j++) acc[i][j] = fzero;

    const u16* pB0 = Bb + (size_t)(colBase + sRow) * ldb + sKg;
    const u16* pB1 = pB0 + (size_t)64 * ldb;
    const u16* pA0 = nullptr; const u16* pA1 = nullptr;
    if (TRF == 0) {
        pA0 = Ab + (size_t)(rowBase + sRow) * lda + sKg;
        pA1 = pA0 + (size_t)64 * lda;
    }

    // swizzled read chunk offsets (elems): phys chunk = (h*4+q)^(mrow&7)
    const int rsw = mrow & 7;
    const int kc0 = (((0 * 4 + q) ^ rsw) << 3);
    const int kc1 = (((1 * 4 + q) ^ rsw) << 3);

    i32x4 a0, a1;
    if (TRF == 1) {
        a0 = loadX(0,  k0, st0);
        a1 = loadX(64, k0, st1);
    }

    for (int kk = k0; kk < k1; kk += 64) {
        if (TRF == 1) {
            *(i32x4*)&lsA[sRow * 64 + sKl]        = a0;
            *(i32x4*)&lsA[(sRow + 64) * 64 + sKl] = a1;
        } else if (TRF == 0) {
            glds16(pA0 + kk, ldA0);
            glds16(pA1 + kk, ldA1);
        } else {
            glds16(aPtr(0,  kk), ldA0);
            glds16(aPtr(64, kk), ldA1);
        }
        glds16(pB0 + kk, ldB0);
        glds16(pB1 + kk, ldB1);
        __syncthreads();
        const int kn = kk + 64;
        if (TRF == 1 && kn < k1) {
            a0 = loadX(0,  kn, st0);
            a1 = loadX(64, kn, st1);
        }
#pragma unroll
        for (int h = 0; h < 2; h++) {
            const int kc = h ? kc1 : kc0;
            bf16x8 af[2], bfr[4];
#pragma unroll
            for (int mi = 0; mi < 2; mi++)
                af[mi] = __builtin_bit_cast(bf16x8,
                    *(const short8*)&lsA[(wr + mi * 16 + mrow) * 64 + kc]);
#pragma unroll
            for (int ni = 0; ni < 4; ni++)
                bfr[ni] = __builtin_bit_cast(bf16x8,
                    *(const short8*)&lsB[(wc + ni * 16 + mrow) * 64 + kc]);
#pragma unroll
            for (int mi = 0; mi < 2; mi++)
#pragma unroll
                for (int ni = 0; ni < 4; ni++)
                    acc[mi][ni] = __builtin_amdgcn_mfma_f32_16x16x32_bf16(
                        af[mi], bfr[ni], acc[mi][ni], 0, 0, 0);
        }
        __syncthreads();
    }

    if (MODE == 5) {
        // fused qkv epilogue: Xb + XT (u16x4 transpose store) + exp-sum.
        u16* XT = const_cast<u16*>(Xres);
        float2* sm = const_cast<float2*>(stats);
        float rsum[2][4] = {{0.f,0.f,0.f,0.f},{0.f,0.f,0.f,0.f}};
#pragma unroll
        for (int mi = 0; mi < 2; mi++) {
#pragma unroll
            for (int ni = 0; ni < 4; ni++) {
                const int col  = colBase + wc + ni * 16 + mrow;
                const int row0 = rowBase + wr + mi * 16 + q * 4;
                u16x4 hv;
#pragma unroll
                for (int r = 0; r < 4; r++) {
                    const u16 h = f2b(acc[mi][ni][r]);
                    hv[r] = h;
                    outB[(size_t)(row0 + r) * ldo + col] = h;
                    rsum[mi][r] += __expf(b2f(h));
                }
                *(u16x4*)(XT + (size_t)(row0 >> 12) * 1048576
                             + (size_t)col * 4096 + (row0 & 4095)) = hv;
            }
        }
#pragma unroll
        for (int mi = 0; mi < 2; mi++)
#pragma unroll
            for (int r = 0; r < 4; r++) {
                float s = rsum[mi][r];
                s += __shfl_xor(s, 1); s += __shfl_xor(s, 2);
                s += __shfl_xor(s, 4); s += __shfl_xor(s, 8);
                if (mrow == 0)
                    atomicAdd(&sm[rowBase + wr + mi * 16 + q * 4 + r].y, s);
            }
        return;
    }

    if (MODE == 6 || MODE == 7) {
        // store + per-row {sum,sumsq} of rounded values -> omstat atomics
        float2* om = const_cast<float2*>(stats);
        float ss[2][4]  = {{0.f,0.f,0.f,0.f},{0.f,0.f,0.f,0.f}};
        float ss2[2][4] = {{0.f,0.f,0.f,0.f},{0.f,0.f,0.f,0.f}};
#pragma unroll
        for (int mi = 0; mi < 2; mi++) {
#pragma unroll
            for (int ni = 0; ni < 4; ni++) {
                const int col = colBase + wc + ni * 16 + mrow;
#pragma unroll
                for (int r = 0; r < 4; r++) {
                    const int row = rowBase + wr + mi * 16 + q * 4 + r;
                    float v = acc[mi][ni][r];
                    if (MODE == 7) {
                        v += bias[col];
                        v = v > 0.f ? v : 0.f;
                    }
                    const u16 h = f2b(v);
                    outB[(size_t)batch * sOB + (size_t)row * ldo + col] = h;
                    const float uf = b2f(h);
                    ss[mi][r]  += uf;
                    ss2[mi][r] += uf * uf;
                }
            }
        }
#pragma unroll
        for (int mi = 0; mi < 2; mi++)
#pragma unroll
            for (int r = 0; r < 4; r++) {
                float s  = ss[mi][r], s2 = ss2[mi][r];
                s  += __shfl_xor(s, 1);  s  += __shfl_xor(s, 2);
                s  += __shfl_xor(s, 4);  s  += __shfl_xor(s, 8);
                s2 += __shfl_xor(s2, 1); s2 += __shfl_xor(s2, 2);
                s2 += __shfl_xor(s2, 4); s2 += __shfl_xor(s2, 8);
                if (mrow == 0) {
                    const int grow = batch * statStride
                                   + rowBase + wr + mi * 16 + q * 4 + r;
                    atomicAdd(&om[grow].x, s);
                    atomicAdd(&om[grow].y, s2);
                }
            }
        return;
    }

    // epilogue: lane holds D[row = q*4+r][col = mrow] per 16x16 tile
    if (MODE == 4) {
        // LN-fold with inline stats: vstat (stats) + omstat (bias ptr)
        const float2* om = (const float2*)bias;
        float mean_[2][4], rstd_[2][4];
#pragma unroll
        for (int mi = 0; mi < 2; mi++)
#pragma unroll
            for (int r = 0; r < 4; r++) {
                const int row = rowBase + wr + mi * 16 + q * 4 + r;
                const float2 vs = stats[row];
                const float2 os = om[row];
                const float s  = vs.x + os.x;
                const float s2 = vs.y + os.y;
                const float mean = s * (1.f / 1024.f);
                const float var  = s2 * (1.f / 1024.f) - mean * mean;
                mean_[mi][r] = mean;
                rstd_[mi][r] = rsqrtf(var + 1e-5f);
            }
#pragma unroll
        for (int mi = 0; mi < 2; mi++) {
#pragma unroll
            for (int ni = 0; ni < 4; ni++) {
                const int col = colBase + wc + ni * 16 + mrow;
#pragma unroll
                for (int r = 0; r < 4; r++) {
                    const int row = rowBase + wr + mi * 16 + q * 4 + r;
                    float v = acc[mi][ni][r];
                    v = rstd_[mi][r] * (v - mean_[mi][r] * g[col]) + be[col]
                        + 2.f * b2f(Xres[(size_t)row * 256 + col]);
                    outB[(size_t)row * ldo + col] = f2b(v);
                }
            }
        }
        return;
    }

#pragma unroll
    for (int mi = 0; mi < 2; mi++) {
#pragma unroll
        for (int ni = 0; ni < 4; ni++) {
            const int col = colBase + wc + ni * 16 + mrow;
#pragma unroll
            for (int r = 0; r < 4; r++) {
                const int row = rowBase + wr + mi * 16 + q * 4 + r;
                float v = acc[mi][ni][r];
                if (MODE == 0) {
                    outB[(size_t)batch * sOB + (size_t)row * ldo + col] = f2b(v);
                } else if (MODE == 1) {
                    outF[((size_t)batch * nKsplit + ks) * sOF
                         + (size_t)row * ldo + col] = v;
                } else if (MODE == 3) {
                    v += bias[col];
                    v = v > 0.f ? v : 0.f;
                    outB[(size_t)row * ldo + col] = f2b(v);
                }
            }
        }
    }
}

// ---------------------------------------------------------------------------
// Transpose (R x Cc) -> (Cc x R) per batch, with dtype conversion.
// ---------------------------------------------------------------------------
template<typename TIN, typename TOUT>
__global__ __launch_bounds__(256)
void transpose_k(const TIN* __restrict__ in, TOUT* __restrict__ out,
                 int R, int Cc, long sIn, long sOut)
{
    __shared__ TOUT tile[32][33];
    const int b = blockIdx.z;
    const TIN* ib = in + (size_t)b * sIn;
    TOUT* ob = out + (size_t)b * sOut;
    const int c0 = blockIdx.x * 32, r0 = blockIdx.y * 32;
    const int tx = threadIdx.x & 31, ty = threadIdx.x >> 5;
#pragma unroll
    for (int i = 0; i < 32; i += 8)
        cvt(ib[(size_t)(r0 + ty + i) * Cc + c0 + tx], tile[ty + i][tx]);
    __syncthreads();
#pragma unroll
    for (int i = 0; i < 32; i += 8)
        ob[(size_t)(c0 + ty + i) * R + r0 + tx] = tile[tx][ty + i];
}

// Zero softmax-sum stats (32768 float2).
__global__ __launch_bounds__(256)
void zerosm_k(float2* __restrict__ p)
{
    p[blockIdx.x * 256 + threadIdx.x] = make_float2(0.f, 0.f);
}

// SXb = exp(Xb) / rowsum (bf16), plus vstat[row] = {sum, sumsq} of Xb.
// One wave per row; 4 waves/block; grid 8192.
__global__ __launch_bounds__(256)
void sxb_k(const u16* __restrict__ Xb, const float2* __restrict__ smst,
           u16* __restrict__ SXb, float2* __restrict__ vstat)
{
    const int wave = threadIdx.x >> 6, lane = threadIdx.x & 63;
    const size_t row = (size_t)blockIdx.x * 4 + wave;
    const u16x4 xb = *(const u16x4*)(Xb + row * 256 + lane * 4);
    const float rs = 1.f / smst[row].y;
    const float x0 = b2f(xb.x), x1 = b2f(xb.y), x2 = b2f(xb.z), x3 = b2f(xb.w);
    u16x4 o = { f2b(__expf(x0) * rs), f2b(__expf(x1) * rs),
                f2b(__expf(x2) * rs), f2b(__expf(x3) * rs) };
    *(u16x4*)(SXb + row * 256 + lane * 4) = o;
    float s  = x0 + x1 + x2 + x3;
    float s2 = x0 * x0 + x1 * x1 + x2 * x2 + x3 * x3;
    for (int d = 32; d > 0; d >>= 1) { s += __shfl_xor(s, d); s2 += __shfl_xor(s2, d); }
    if (lane == 0) vstat[row] = make_float2(s, s2);
}

// ---------------------------------------------------------------------------
// Fused LN256 + transpose; WRITE_VB also direct-stores vstat (full-row sums).
// ---------------------------------------------------------------------------
template<typename OUTT, bool WRITE_VB>
__global__ __launch_bounds__(256)
void ln256t_k(const u16* __restrict__ Tb, const float* __restrict__ g,
              const float* __restrict__ be, u16* __restrict__ Vb,
              OUTT* __restrict__ outT, float2* __restrict__ vstat)
{
    constexpr int STRIDE = (sizeof(OUTT) == 2) ? 266 : 261;
    __shared__ OUTT tile[32 * STRIDE];
    const int wid = threadIdx.x >> 6, lane = threadIdx.x & 63;
    const int bx = blockIdx.x;
    const size_t r0 = (size_t)bx * 32;
    const int b  = bx >> 7;
    const int n0 = (bx & 127) * 32;

#pragma unroll
    for (int j = 0; j < 8; j++) {
        const int lr = wid * 8 + j;
        const size_t row = r0 + lr;
        const u16x4 tb = *(const u16x4*)(Tb + row * 256 + lane * 4);
        const float x0 = b2f(tb.x), x1 = b2f(tb.y), x2 = b2f(tb.z), x3 = b2f(tb.w);
        float s  = x0 + x1 + x2 + x3;
        float s2 = x0 * x0 + x1 * x1 + x2 * x2 + x3 * x3;
        for (int o = 32; o > 0; o >>= 1) { s += __shfl_xor(s, o); s2 += __shfl_xor(s2, o); }
        const float mean = s * (1.f / 256.f);
        const float var  = s2 * (1.f / 256.f) - mean * mean;
        const float rstd = rsqrtf(var + 1e-5f);
        const int c = lane * 4;
        float4 ov = { (x0 - mean) * rstd * g[c + 0] + be[c + 0],
                      (x1 - mean) * rstd * g[c + 1] + be[c + 1],
                      (x2 - mean) * rstd * g[c + 2] + be[c + 2],
                      (x3 - mean) * rstd * g[c + 3] + be[c + 3] };
        if (WRITE_VB) {
            u16x4 vb = { f2b(ov.x), f2b(ov.y), f2b(ov.z), f2b(ov.w) };
            *(u16x4*)(Vb + row * 256 + c) = vb;
            const float u0 = b2f(vb.x), u1 = b2f(vb.y),
                        u2 = b2f(vb.z), u3 = b2f(vb.w);
            float vs  = u0 + u1 + u2 + u3;
            float vs2 = u0 * u0 + u1 * u1 + u2 * u2 + u3 * u3;
            for (int o = 32; o > 0; o >>= 1) { vs += __shfl_xor(vs, o); vs2 += __shfl_xor(vs2, o); }
            if (lane == 0) vstat[row] = make_float2(vs, vs2);
        }
        OUTT* tl = &tile[lr * STRIDE + c];
        cvt(ov.x, tl[0]); cvt(ov.y, tl[1]); cvt(ov.z, tl[2]); cvt(ov.w, tl[3]);
    }
    __syncthreads();

    const int c = threadIdx.x;
    OUTT* dst = outT + ((size_t)b * 256 + c) * 4096 + n0;
    if (sizeof(OUTT) == 2) {
#pragma unroll
        for (int k = 0; k < 4; k++) {
            u16x8 v;
#pragma unroll
            for (int i = 0; i < 8; i++) v[i] = *(const u16*)&tile[(k * 8 + i) * STRIDE + c];
            *(u16x8*)((u16*)dst + k * 8) = v;
        }
    } else {
#pragma unroll
        for (int k = 0; k < 8; k++) {
            float4 v;
            v.x = *(const float*)&tile[(k * 4 + 0) * STRIDE + c];
            v.y = *(const float*)&tile[(k * 4 + 1) * STRIDE + c];
            v.z = *(const float*)&tile[(k * 4 + 2) * STRIDE + c];
            v.w = *(const float*)&tile[(k * 4 + 3) * STRIDE + c];
            *(float4*)((float*)dst + k * 4) = v;
        }
    }
}

// Reduce 16 split-K partial fp32 ctx buffers -> bf16; also zeroes omstat.
__global__ __launch_bounds__(256)
void ctxreduce_k(const float* __restrict__ ctxp, u16* __restrict__ ctxb,
                 float2* __restrict__ om)
{
    const int i = blockIdx.x * 256 + threadIdx.x;
    if (i < 32768) om[i] = make_float2(0.f, 0.f);
    const int batch  = i >> 14;
    const int within = i & 16383;
    const float4* src = (const float4*)ctxp + (size_t)batch * 16 * 16384 + within;
    float4 s = {0.f, 0.f, 0.f, 0.f};
#pragma unroll
    for (int ks = 0; ks < 16; ks++) {
        const float4 v = src[(size_t)ks * 16384];
        s.x += v.x; s.y += v.y; s.z += v.z; s.w += v.w;
    }
    u16x4 o = { f2b(s.x), f2b(s.y), f2b(s.z), f2b(s.w) };
    ((u16x4*)ctxb)[i] = o;
}

// Convert Wqkv and Wmlp fp32->bf16 in one launch (Wres handled by wresprep_k).
__global__ __launch_bounds__(256)
void wconv_k(const float* __restrict__ Wq, const float* __restrict__ Wm,
             u16* __restrict__ oq, u16* __restrict__ om)
{
    const int i = blockIdx.x * 256 + threadIdx.x;
    const float* src; u16* dst; int j;
    if (i < 16384) { src = Wq; dst = oq; j = i; }
    else           { src = Wm; dst = om; j = i - 16384; }
    const float4 v = ((const float4*)src)[j];
    u16x4 o = { f2b(v.x), f2b(v.y), f2b(v.z), f2b(v.w) };
    ((u16x4*)dst)[j] = o;
}

// LN-fold prep: Wr_b[c,k] = bf16(Wres[c,k]*g1[k]);
// sg[c] = sum_k g1[k]*Wres[c,k];  br[c] = sum_k be1[k]*Wres[c,k].
__global__ __launch_bounds__(256)
void wresprep_k(const float* __restrict__ Wres, const float* __restrict__ g1,
                const float* __restrict__ be1, u16* __restrict__ Wr_b,
                float* __restrict__ sg, float* __restrict__ br)
{
    const int wv = threadIdx.x >> 6, lane = threadIdx.x & 63;
    const int row = blockIdx.x * 4 + wv;
    const float* src = Wres + (size_t)row * 1024;
    float s = 0.f, b = 0.f;
#pragma unroll
    for (int j = 0; j < 4; j++) {
        const int c = j * 256 + lane * 4;
        const float4 w  = *(const float4*)(src + c);
        const float4 gg = *(const float4*)(g1 + c);
        const float4 bb = *(const float4*)(be1 + c);
        const float4 wg = { w.x * gg.x, w.y * gg.y, w.z * gg.z, w.w * gg.w };
        u16x4 o = { f2b(wg.x), f2b(wg.y), f2b(wg.z), f2b(wg.w) };
        *(u16x4*)(Wr_b + (size_t)row * 1024 + c) = o;
        s += wg.x + wg.y + wg.z + wg.w;
        b += w.x * bb.x + w.y * bb.y + w.z * bb.z + w.w * bb.w;
    }
    for (int o = 32; o > 0; o >>= 1) { s += __shfl_xor(s, o); b += __shfl_xor(b, o); }
    if (lane == 0) { sg[row] = s; br[row] = b; }
}

extern "C" void kernel_launch(void* const* d_in, const int* in_sizes, int n_in,
                              void* d_out, int out_size, void* d_ws, size_t ws_size,
                              hipStream_t stream)
{
    (void)in_sizes; (void)n_in; (void)out_size; (void)ws_size;
    const float* x    = (const float*)d_in[0];
    const float* Wqkv = (const float*)d_in[1];
    const float* Wmlp = (const float*)d_in[2];
    const float* bmlp = (const float*)d_in[3];
    const float* g1   = (const float*)d_in[4];
    const float* be1  = (const float*)d_in[5];
    const float* Wres = (const float*)d_in[6];
    const float* g2   = (const float*)d_in[7];
    const float* be2  = (const float*)d_in[8];

    // workspace (~190 MiB of 256)
    char* ws = (char*)d_ws;
    u16*    Xb   = (u16*)ws;    ws += (size_t)16777216;   // (32768,256)
    u16*    XT   = (u16*)ws;    ws += (size_t)16777216;   // (B,256,4096)
    u16*    SXb  = (u16*)ws;    ws += (size_t)16777216;   // (32768,256) softmax
    u16*    Vb   = (u16*)ws;    ws += (size_t)16777216;   // (32768,256)
    u16*    VT2  = (u16*)ws;    ws += (size_t)16777216;   // (B,256,4096)
    u16*    OUT  = (u16*)ws;    ws += (size_t)16777216;   // (32768,256)
    u16*    MLPo = (u16*)ws;    ws += (size_t)33554432;   // (32768,512)
    u16*    Tb   = (u16*)ws;    ws += (size_t)16777216;   // (32768,256)
    float*  ctxp = (float*)ws;  ws += (size_t)33554432;   // (B*16,256,256) fp32
    u16*    ctxb = (u16*)ws;    ws += (size_t)1048576;    // (B,256,256)
    float2* smst = (float2*)ws; ws += (size_t)262144;     // (32768) {0,sumexp}
    float2* vstat= (float2*)ws; ws += (size_t)262144;     // (32768) {s,s2} of V
    float2* omst = (float2*)ws; ws += (size_t)262144;     // (32768) {s,s2} OUT+MLP
    u16*    Wq_b = (u16*)ws;    ws += (size_t)131072;
    u16*    Wm_b = (u16*)ws;    ws += (size_t)524288;
    u16*    Wr_b = (u16*)ws;    ws += (size_t)524288;
    float*  sg   = (float*)ws;  ws += (size_t)1024;       // (256) sum g*Wres
    float*  br   = (float*)ws;  ws += (size_t)1024;       // (256) sum be*Wres
    u16*    xt   = MLPo;  // alias: xt dead before MLPo's first write

    // 0. weights fp32 -> bf16 (+ LN-fold prep for Wres) + zero softmax sums
    wconv_k<<<dim3(320), 256, 0, stream>>>(Wqkv, Wmlp, Wq_b, Wm_b);
    wresprep_k<<<dim3(64), 256, 0, stream>>>(Wres, g1, be1, Wr_b, sg, br);
    zerosm_k<<<dim3(128), 256, 0, stream>>>(smst);

    // 1. xt = transpose(x): per batch (256,4096) fp32 -> (4096,256) bf16
    transpose_k<float, u16><<<dim3(128, 8, 8), 256, 0, stream>>>(
        x, xt, 256, 4096, 256L * 4096, 4096L * 256);

    // 2. fused qkv: Xb = xt @ Wqkv^T, XT = Xb^T, smst.y = rowsum exp(Xb)
    gemm_bt<5, 0><<<dim3(2, 256, 1), 512, 0, stream>>>(
        xt, nullptr, nullptr, 256, 0, 0, 0, Wq_b, 256, 0, 0, 0, 256, 1,
        nullptr, Xb, 0, 0, 256, XT, nullptr, smst, nullptr, nullptr);

    // 2b. SXb = softmax(Xb) (iteration-invariant), vstat = stats of Xb
    sxb_k<<<dim3(8192), 256, 0, stream>>>(Xb, smst, SXb, vstat);

    const u16* VTcur = XT;
    const u16* Vcur  = Xb;

    for (int it = 0; it < 2; ++it) {
        // ctx split-K=16 partials
        gemm_bt<1, 0><<<dim3(2, 2, 128), 512, 0, stream>>>(
            VTcur, nullptr, nullptr, 4096, 0, 0, 0, XT, 4096,
            1048576, 1048576, 0, 256, 16,
            ctxp, nullptr, 65536, 0, 256, nullptr, nullptr, nullptr, nullptr, nullptr);
        ctxreduce_k<<<dim3(512), 256, 0, stream>>>(ctxp, ctxb, omst);

        // OUT = SXb @ ctxT^T  [per batch 4096x256, K=256]; omstat accumulation
        gemm_bt<6, 0><<<dim3(2, 32, 8), 512, 0, stream>>>(
            SXb, nullptr, nullptr, 256, 0, 0, 0, ctxb, 256,
            1048576, 65536, 4096, 256, 1,
            nullptr, OUT, 0, 1048576, 256, nullptr, nullptr, omst, nullptr, nullptr);

        // MLPo = relu([OUT|Vcur] @ Wmlp^T + b); omstat accumulation
        gemm_bt<7, 3><<<dim3(4, 256, 1), 512, 0, stream>>>(
            OUT, Vcur, nullptr, 256, 256, 0, 256, Wm_b, 512, 0, 0, 0, 512, 1,
            nullptr, MLPo, 0, 0, 512, nullptr, bmlp, omst, nullptr, nullptr);

        // Tb = LN1024([OUT|Vcur|MLPo]) @ Wres^T + 2*Xb; stats inline from
        // vstat + omst (stats1024 pass eliminated)
        gemm_bt<4, 2><<<dim3(2, 256, 1), 512, 0, stream>>>(
            OUT, Vcur, MLPo, 256, 256, 512, 0, Wr_b, 1024, 0, 0, 0, 1024, 1,
            nullptr, Tb, 0, 0, 256, Xb, (const float*)omst, vstat, sg, br);

        // LN256 + transpose fused (it0 also writes vstat for Vb)
        if (it == 0) {
            ln256t_k<u16, true><<<dim3(1024), 256, 0, stream>>>(
                Tb, g2, be2, Vb, VT2, vstat);
            VTcur = VT2;
            Vcur  = Vb;
        } else {
            ln256t_k<float, false><<<dim3(1024), 256, 0, stream>>>(
                Tb, g2, be2, nullptr, (float*)d_out, nullptr);
        }
    }
}

// Round 11
// 333.912 us; speedup vs baseline: 1.1159x; 1.1159x over previous
//
#include <hip/hip_runtime.h>
#include <cstdint>
#include <cstddef>

// IT_Fast_Attn: B=8, C=256, N=4096, 2 iterations. fp32 I/O, bf16 compute.
// Round 20: REVERT to r17 (champion, 355.4us; r18/r19 stats-fusion bundle
// regressed to 372.6) + T1 bijective XCD swizzle in gemm_bt.
//   r19 counters: ctx GEMM 41us @ 36% HBM / 15% MfmaUtil, FETCH 67MB vs
//   32MB unique -> partner blocks sharing A/B panels land on different
//   XCDs (round-robin dispatch), re-reads miss the private L2 and pay
//   full HBM latency inside the vmcnt(0) drain (our critical path).
//   Swizzle: lin=(x + gx*(y + gy*z)); swz=(lin&7)*(nwg/8)+(lin>>3)
//   (bijective: all grids 512/1024, %8==0) -> each XCD gets a contiguous
//   tile chunk; partner tiles co-resident on one XCD -> L2 hits.
// Swizzle (LDS, rule #21 both-sides): global chunk (t&7)^(sRow&7), read
// chunk (h*4+q)^(mrow&7); phys chunk p of row r = logical p^(r&7).

using u16 = unsigned short;
using short8 = __attribute__((ext_vector_type(8))) short;
using bf16x8 = __attribute__((ext_vector_type(8))) __bf16;
using f32x4  = __attribute__((ext_vector_type(4))) float;
using i32x4  = __attribute__((ext_vector_type(4))) int;
using u16x4  = __attribute__((ext_vector_type(4))) u16;
using u16x8  = __attribute__((ext_vector_type(8))) u16;

__device__ __forceinline__ float b2f(u16 u) {
    union { unsigned u32; float f; } c; c.u32 = ((unsigned)u) << 16; return c.f;
}
__device__ __forceinline__ u16 f2b(float f) {
    union { float f; unsigned u; } c; c.f = f;
    unsigned r = c.u + 0x7FFFu + ((c.u >> 16) & 1u);
    return (u16)(r >> 16);
}
__device__ __forceinline__ void cvt(u16 a,  u16& o)   { o = a; }
__device__ __forceinline__ void cvt(float a, u16& o)  { o = f2b(a); }
__device__ __forceinline__ void cvt(float a, float& o){ o = a; }
__device__ __forceinline__ void cvt(u16 a,  float& o) { o = b2f(a); }

// async global->LDS, 16 B/lane; lds dest = wave-uniform base + lane*16.
__device__ __forceinline__ void glds16(const u16* g, short* l) {
    __builtin_amdgcn_global_load_lds(
        (const __attribute__((address_space(1))) void*)g,
        (__attribute__((address_space(3))) void*)l, 16, 0, 0);
}

// ---------------------------------------------------------------------------
// BT GEMM: C[row,col] = sum_k A[row,k] * B[col,k].  BM=BN=128, BK=64.
// 512 threads = 8 waves in 4x2; wave covers 32 rows x 64 cols; 16 MFMAs/iter
// (2 mi x 4 ni x 2 k-halves of 16x16x32 bf16). COL-fastest tile order +
// T1 XCD swizzle (contiguous tile chunk per XCD -> partner-tile L2 reuse).
// Staging: wave w DMAs rows [w*8, w*8+8) of each 64-row half via
// global_load_lds (lane l -> row w*8+(l>>3), phys chunk l&7, global chunk
// (l&7)^((l>>3)&7)).  LDS stride 64 shorts, XOR-swizzled chunks.
// TRF: 0 plain | 1 softmax exp(a)*(1/sum) from stats[].y (A reg-staged) |
//      2 three-source region split over A|A2|A3 | 3 two-source split.
// MODE: 0 store bf16 | 1 fp32 partial per ks-slice | 3 +bias,relu,bf16
//       | 4 epilogue LN-fold | 5 fused qkv: Xb + XT(via Xres ptr) +
//         per-row exp-sum atomics into stats[].y.
// ---------------------------------------------------------------------------
template<int MODE, int TRF>
__global__ __launch_bounds__(512)
void gemm_bt(const u16* __restrict__ A, const u16* __restrict__ A2,
             const u16* __restrict__ A3,
             int lda, int lda2, int lda3, int kSplit,
             const u16* __restrict__ B, int ldb, long strA, long strB,
             int statStride, int kChunk, int nKsplit,
             float* __restrict__ outF, u16* __restrict__ outB,
             long sOF, long sOB, int ldo,
             const u16* __restrict__ Xres,
             const float* __restrict__ bias,
             const float2* __restrict__ stats,
             const float* __restrict__ g, const float* __restrict__ be)
{
    __shared__ short lsA[128 * 64];
    __shared__ short lsB[128 * 64];

    // T1: bijective XCD swizzle (every grid here has nwg % 8 == 0)
    const unsigned gx = gridDim.x, gy = gridDim.y;
    const unsigned nwg = gx * gy * gridDim.z;
    unsigned lin = blockIdx.x + gx * (blockIdx.y + gy * blockIdx.z);
    lin = (lin & 7u) * (nwg >> 3) + (lin >> 3);
    const unsigned sbx = lin % gx;
    const unsigned rest = lin / gx;
    const unsigned sby = rest % gy;
    const unsigned sbz = rest / gy;

    const int bz    = (int)sbz;
    const int batch = bz / nKsplit;
    const int ks    = bz - batch * nKsplit;
    const u16* Ab = A + (size_t)batch * strA;
    const u16* Bb = B + (size_t)batch * strB;
    const int colBase = (int)sbx * 128;   // col-fastest tile order
    const int rowBase = (int)sby * 128;
    const int k0 = ks * kChunk;
    const int k1 = k0 + kChunk;

    const int t    = threadIdx.x;
    const int sRow = t >> 3;                         // 0..63
    const int sKl  = (t & 7) << 3;                   // linear lds chunk (elems)
    const int sKg  = (((t & 7) ^ (sRow & 7)) << 3);  // swizzled global chunk

    const int lane = t & 63;
    const int w    = t >> 6;           // 0..7
    const int wr   = (w >> 1) * 32;    // wave row base
    const int wc   = (w & 1) * 64;     // wave col base
    const int mrow = lane & 15;
    const int q    = lane >> 4;

    // wave-uniform LDS DMA destinations (rows w*8..w*8+7 of each half)
    short* ldA0 = &lsA[w * 512];
    short* ldA1 = &lsA[4096 + w * 512];
    short* ldB0 = &lsB[w * 512];
    short* ldB1 = &lsB[4096 + w * 512];

    float2 st0 = {0.f, 0.f}, st1 = {0.f, 0.f};
    if (TRF == 1) {
        const int sb = batch * statStride + rowBase;
        const float2 t0 = stats[sb + sRow];
        const float2 t1 = stats[sb + sRow + 64];
        st0 = make_float2(0.f, 1.f / t0.y);   // y holds accumulated sum(exp)
        st1 = make_float2(0.f, 1.f / t1.y);
    }

    // per-lane global A pointer for window base kn (region from kn; the
    // swizzled chunk sKg stays inside [kn, kn+64))
    auto aPtr = [&](int rloc, int kn) -> const u16* {
        const int arow = rowBase + rloc + sRow;
        if (TRF == 2) {
            if (kn < 256)      return A  + (size_t)arow * lda  + kn + sKg;
            else if (kn < 512) return A2 + (size_t)arow * lda2 + (kn - 256) + sKg;
            else               return A3 + (size_t)arow * lda3 + (kn - 512) + sKg;
        } else if (TRF == 3) {
            if (kn < kSplit)   return Ab + (size_t)arow * lda + kn + sKg;
            return A2 + (size_t)arow * lda2 + (kn - kSplit) + sKg;
        }
        return Ab + (size_t)arow * lda + kn + sKg;
    };
    // TRF==1 reg path: load swizzled global chunk, transform (row-only stats,
    // safe under chunk permutation), ds_write to the LINEAR slot.
    auto loadX = [&](int rloc, int kn, float2 st) -> i32x4 {
        const int arow = rowBase + rloc + sRow;
        i32x4 raw = *(const i32x4*)(Ab + (size_t)arow * lda + kn + sKg);
        short8 h = __builtin_bit_cast(short8, raw);
        short8 o;
#pragma unroll
        for (int i = 0; i < 8; i++) {
            float v = b2f((u16)h[i]);
            v = __expf(v - st.x) * st.y;
            o[i] = (short)f2b(v);
        }
        return __builtin_bit_cast(i32x4, o);
    };

    const f32x4 fzero = {0.f, 0.f, 0.f, 0.f};
    f32x4 acc[2][4];
#pragma unroll
    for (int i = 0; i < 2; i++)
#pragma unroll
        for (int j = 0; j < 4; j++) acc[i][j] = fzero;

    const u16* pB0 = Bb + (size_t)(colBase + sRow) * ldb + sKg;
    const u16* pB1 = pB0 + (size_t)64 * ldb;
    const u16* pA0 = nullptr; const u16* pA1 = nullptr;
    if (TRF == 0) {
        pA0 = Ab + (size_t)(rowBase + sRow) * lda + sKg;
        pA1 = pA0 + (size_t)64 * lda;
    }

    // swizzled read chunk offsets (elems): phys chunk = (h*4+q)^(mrow&7)
    const int rsw = mrow & 7;
    const int kc0 = (((0 * 4 + q) ^ rsw) << 3);
    const int kc1 = (((1 * 4 + q) ^ rsw) << 3);

    i32x4 a0, a1;
    if (TRF == 1) {
        a0 = loadX(0,  k0, st0);
        a1 = loadX(64, k0, st1);
    }

    for (int kk = k0; kk < k1; kk += 64) {
        if (TRF == 1) {
            *(i32x4*)&lsA[sRow * 64 + sKl]        = a0;
            *(i32x4*)&lsA[(sRow + 64) * 64 + sKl] = a1;
        } else if (TRF == 0) {
            glds16(pA0 + kk, ldA0);
            glds16(pA1 + kk, ldA1);
        } else {
            glds16(aPtr(0,  kk), ldA0);
            glds16(aPtr(64, kk), ldA1);
        }
        glds16(pB0 + kk, ldB0);
        glds16(pB1 + kk, ldB1);
        __syncthreads();
        const int kn = kk + 64;
        if (TRF == 1 && kn < k1) {
            a0 = loadX(0,  kn, st0);
            a1 = loadX(64, kn, st1);
        }
#pragma unroll
        for (int h = 0; h < 2; h++) {
            const int kc = h ? kc1 : kc0;
            bf16x8 af[2], bfr[4];
#pragma unroll
            for (int mi = 0; mi < 2; mi++)
                af[mi] = __builtin_bit_cast(bf16x8,
                    *(const short8*)&lsA[(wr + mi * 16 + mrow) * 64 + kc]);
#pragma unroll
            for (int ni = 0; ni < 4; ni++)
                bfr[ni] = __builtin_bit_cast(bf16x8,
                    *(const short8*)&lsB[(wc + ni * 16 + mrow) * 64 + kc]);
#pragma unroll
            for (int mi = 0; mi < 2; mi++)
#pragma unroll
                for (int ni = 0; ni < 4; ni++)
                    acc[mi][ni] = __builtin_amdgcn_mfma_f32_16x16x32_bf16(
                        af[mi], bfr[ni], acc[mi][ni], 0, 0, 0);
        }
        __syncthreads();
    }

    if (MODE == 5) {
        // fused qkv epilogue: Xb (scalar), XT (u16x4: 4 consecutive rows =
        // 4 consecutive n at fixed col), per-row sum(exp) -> atomicAdd.
        u16* XT = const_cast<u16*>(Xres);
        float2* sm = const_cast<float2*>(stats);
        float rsum[2][4] = {{0.f,0.f,0.f,0.f},{0.f,0.f,0.f,0.f}};
#pragma unroll
        for (int mi = 0; mi < 2; mi++) {
#pragma unroll
            for (int ni = 0; ni < 4; ni++) {
                const int col  = colBase + wc + ni * 16 + mrow;
                const int row0 = rowBase + wr + mi * 16 + q * 4;
                u16x4 hv;
#pragma unroll
                for (int r = 0; r < 4; r++) {
                    const u16 h = f2b(acc[mi][ni][r]);
                    hv[r] = h;
                    outB[(size_t)(row0 + r) * ldo + col] = h;
                    rsum[mi][r] += __expf(b2f(h));
                }
                *(u16x4*)(XT + (size_t)(row0 >> 12) * 1048576
                             + (size_t)col * 4096 + (row0 & 4095)) = hv;
            }
        }
#pragma unroll
        for (int mi = 0; mi < 2; mi++)
#pragma unroll
            for (int r = 0; r < 4; r++) {
                float s = rsum[mi][r];
                s += __shfl_xor(s, 1); s += __shfl_xor(s, 2);
                s += __shfl_xor(s, 4); s += __shfl_xor(s, 8);
                if (mrow == 0)
                    atomicAdd(&sm[rowBase + wr + mi * 16 + q * 4 + r].y, s);
            }
        return;
    }

    // epilogue: lane holds D[row = q*4+r][col = mrow] per 16x16 tile
#pragma unroll
    for (int mi = 0; mi < 2; mi++) {
#pragma unroll
        for (int ni = 0; ni < 4; ni++) {
            const int col = colBase + wc + ni * 16 + mrow;
#pragma unroll
            for (int r = 0; r < 4; r++) {
                const int row = rowBase + wr + mi * 16 + q * 4 + r;
                float v = acc[mi][ni][r];
                if (MODE == 0) {
                    outB[(size_t)batch * sOB + (size_t)row * ldo + col] = f2b(v);
                } else if (MODE == 1) {
                    outF[((size_t)batch * nKsplit + ks) * sOF
                         + (size_t)row * ldo + col] = v;
                } else if (MODE == 3) {
                    v += bias[col];
                    v = v > 0.f ? v : 0.f;
                    outB[(size_t)row * ldo + col] = f2b(v);
                } else if (MODE == 4) {
                    // LN-fold: rstd*(acc - mu*sg[col]) + br[col] + 2*Xres
                    const float2 ln = stats[row];   // {mean, rstd}
                    v = ln.y * (v - ln.x * g[col]) + be[col]
                        + 2.f * b2f(Xres[(size_t)row * 256 + col]);
                    outB[(size_t)row * ldo + col] = f2b(v);
                }
            }
        }
    }
}

// ---------------------------------------------------------------------------
// Transpose (R x Cc) -> (Cc x R) per batch, with dtype conversion.
// ---------------------------------------------------------------------------
template<typename TIN, typename TOUT>
__global__ __launch_bounds__(256)
void transpose_k(const TIN* __restrict__ in, TOUT* __restrict__ out,
                 int R, int Cc, long sIn, long sOut)
{
    __shared__ TOUT tile[32][33];
    const int b = blockIdx.z;
    const TIN* ib = in + (size_t)b * sIn;
    TOUT* ob = out + (size_t)b * sOut;
    const int c0 = blockIdx.x * 32, r0 = blockIdx.y * 32;
    const int tx = threadIdx.x & 31, ty = threadIdx.x >> 5;
#pragma unroll
    for (int i = 0; i < 32; i += 8)
        cvt(ib[(size_t)(r0 + ty + i) * Cc + c0 + tx], tile[ty + i][tx]);
    __syncthreads();
#pragma unroll
    for (int i = 0; i < 32; i += 8)
        ob[(size_t)(c0 + ty + i) * R + r0 + tx] = tile[tx][ty + i];
}

// Zero softmax-sum stats (32768 float2).
__global__ __launch_bounds__(256)
void zerosm_k(float2* __restrict__ p)
{
    p[blockIdx.x * 256 + threadIdx.x] = make_float2(0.f, 0.f);
}

// Per-row LN stats of virtual row [OUT(256)|V(256)|MLPo(512)]: {mean, rstd}.
__global__ __launch_bounds__(256)
void stats1024_k(const u16* __restrict__ OUT, const u16* __restrict__ V,
                 const u16* __restrict__ MLPo, float2* __restrict__ st)
{
    const int wave = threadIdx.x >> 6, lane = threadIdx.x & 63;
    const size_t row = (size_t)blockIdx.x * 4 + wave;
    const int c = lane * 16;
    const u16* src;
    if (c < 256)       src = OUT  + row * 256 + c;
    else if (c < 512)  src = V    + row * 256 + (c - 256);
    else               src = MLPo + row * 512 + (c - 512);
    short8 r0 = *(const short8*)(src);
    short8 r1 = *(const short8*)(src + 8);
    float s = 0.f, s2 = 0.f;
#pragma unroll
    for (int i = 0; i < 8; i++) {
        const float a = b2f((u16)r0[i]), b = b2f((u16)r1[i]);
        s += a + b; s2 += a * a + b * b;
    }
    for (int o = 32; o > 0; o >>= 1) { s += __shfl_xor(s, o); s2 += __shfl_xor(s2, o); }
    const float mean = s * (1.f / 1024.f);
    const float var  = s2 * (1.f / 1024.f) - mean * mean;
    if (lane == 0) st[row] = make_float2(mean, rsqrtf(var + 1e-5f));
}

// ---------------------------------------------------------------------------
// Fused LN256 + transpose (unchanged from r5).
// ---------------------------------------------------------------------------
template<typename OUTT, bool WRITE_VB>
__global__ __launch_bounds__(256)
void ln256t_k(const u16* __restrict__ Tb, const float* __restrict__ g,
              const float* __restrict__ be, u16* __restrict__ Vb,
              OUTT* __restrict__ outT)
{
    constexpr int STRIDE = (sizeof(OUTT) == 2) ? 266 : 261;
    __shared__ OUTT tile[32 * STRIDE];
    const int wid = threadIdx.x >> 6, lane = threadIdx.x & 63;
    const int bx = blockIdx.x;
    const size_t r0 = (size_t)bx * 32;
    const int b  = bx >> 7;
    const int n0 = (bx & 127) * 32;

#pragma unroll
    for (int j = 0; j < 8; j++) {
        const int lr = wid * 8 + j;
        const size_t row = r0 + lr;
        const u16x4 tb = *(const u16x4*)(Tb + row * 256 + lane * 4);
        const float x0 = b2f(tb.x), x1 = b2f(tb.y), x2 = b2f(tb.z), x3 = b2f(tb.w);
        float s  = x0 + x1 + x2 + x3;
        float s2 = x0 * x0 + x1 * x1 + x2 * x2 + x3 * x3;
        for (int o = 32; o > 0; o >>= 1) { s += __shfl_xor(s, o); s2 += __shfl_xor(s2, o); }
        const float mean = s * (1.f / 256.f);
        const float var  = s2 * (1.f / 256.f) - mean * mean;
        const float rstd = rsqrtf(var + 1e-5f);
        const int c = lane * 4;
        float4 ov = { (x0 - mean) * rstd * g[c + 0] + be[c + 0],
                      (x1 - mean) * rstd * g[c + 1] + be[c + 1],
                      (x2 - mean) * rstd * g[c + 2] + be[c + 2],
                      (x3 - mean) * rstd * g[c + 3] + be[c + 3] };
        if (WRITE_VB) {
            u16x4 vb = { f2b(ov.x), f2b(ov.y), f2b(ov.z), f2b(ov.w) };
            *(u16x4*)(Vb + row * 256 + c) = vb;
        }
        OUTT* tl = &tile[lr * STRIDE + c];
        cvt(ov.x, tl[0]); cvt(ov.y, tl[1]); cvt(ov.z, tl[2]); cvt(ov.w, tl[3]);
    }
    __syncthreads();

    const int c = threadIdx.x;
    OUTT* dst = outT + ((size_t)b * 256 + c) * 4096 + n0;
    if (sizeof(OUTT) == 2) {
#pragma unroll
        for (int k = 0; k < 4; k++) {
            u16x8 v;
#pragma unroll
            for (int i = 0; i < 8; i++) v[i] = *(const u16*)&tile[(k * 8 + i) * STRIDE + c];
            *(u16x8*)((u16*)dst + k * 8) = v;
        }
    } else {
#pragma unroll
        for (int k = 0; k < 8; k++) {
            float4 v;
            v.x = *(const float*)&tile[(k * 4 + 0) * STRIDE + c];
            v.y = *(const float*)&tile[(k * 4 + 1) * STRIDE + c];
            v.z = *(const float*)&tile[(k * 4 + 2) * STRIDE + c];
            v.w = *(const float*)&tile[(k * 4 + 3) * STRIDE + c];
            *(float4*)((float*)dst + k * 4) = v;
        }
    }
}

// Reduce 16 split-K partial fp32 ctx buffers -> bf16.
__global__ __launch_bounds__(256)
void ctxreduce_k(const float* __restrict__ ctxp, u16* __restrict__ ctxb)
{
    const int i = blockIdx.x * 256 + threadIdx.x;
    const int batch  = i >> 14;
    const int within = i & 16383;
    const float4* src = (const float4*)ctxp + (size_t)batch * 16 * 16384 + within;
    float4 s = {0.f, 0.f, 0.f, 0.f};
#pragma unroll
    for (int ks = 0; ks < 16; ks++) {
        const float4 v = src[(size_t)ks * 16384];
        s.x += v.x; s.y += v.y; s.z += v.z; s.w += v.w;
    }
    u16x4 o = { f2b(s.x), f2b(s.y), f2b(s.z), f2b(s.w) };
    ((u16x4*)ctxb)[i] = o;
}

// Convert Wqkv and Wmlp fp32->bf16 in one launch (Wres handled by wresprep_k).
__global__ __launch_bounds__(256)
void wconv_k(const float* __restrict__ Wq, const float* __restrict__ Wm,
             u16* __restrict__ oq, u16* __restrict__ om)
{
    const int i = blockIdx.x * 256 + threadIdx.x;
    const float* src; u16* dst; int j;
    if (i < 16384) { src = Wq; dst = oq; j = i; }
    else           { src = Wm; dst = om; j = i - 16384; }
    const float4 v = ((const float4*)src)[j];
    u16x4 o = { f2b(v.x), f2b(v.y), f2b(v.z), f2b(v.w) };
    ((u16x4*)dst)[j] = o;
}

// LN-fold prep: Wr_b[c,k] = bf16(Wres[c,k]*g1[k]);
// sg[c] = sum_k g1[k]*Wres[c,k];  br[c] = sum_k be1[k]*Wres[c,k].
__global__ __launch_bounds__(256)
void wresprep_k(const float* __restrict__ Wres, const float* __restrict__ g1,
                const float* __restrict__ be1, u16* __restrict__ Wr_b,
                float* __restrict__ sg, float* __restrict__ br)
{
    const int wv = threadIdx.x >> 6, lane = threadIdx.x & 63;
    const int row = blockIdx.x * 4 + wv;
    const float* src = Wres + (size_t)row * 1024;
    float s = 0.f, b = 0.f;
#pragma unroll
    for (int j = 0; j < 4; j++) {
        const int c = j * 256 + lane * 4;
        const float4 w  = *(const float4*)(src + c);
        const float4 gg = *(const float4*)(g1 + c);
        const float4 bb = *(const float4*)(be1 + c);
        const float4 wg = { w.x * gg.x, w.y * gg.y, w.z * gg.z, w.w * gg.w };
        u16x4 o = { f2b(wg.x), f2b(wg.y), f2b(wg.z), f2b(wg.w) };
        *(u16x4*)(Wr_b + (size_t)row * 1024 + c) = o;
        s += wg.x + wg.y + wg.z + wg.w;
        b += w.x * bb.x + w.y * bb.y + w.z * bb.z + w.w * bb.w;
    }
    for (int o = 32; o > 0; o >>= 1) { s += __shfl_xor(s, o); b += __shfl_xor(b, o); }
    if (lane == 0) { sg[row] = s; br[row] = b; }
}

extern "C" void kernel_launch(void* const* d_in, const int* in_sizes, int n_in,
                              void* d_out, int out_size, void* d_ws, size_t ws_size,
                              hipStream_t stream)
{
    (void)in_sizes; (void)n_in; (void)out_size; (void)ws_size;
    const float* x    = (const float*)d_in[0];
    const float* Wqkv = (const float*)d_in[1];
    const float* Wmlp = (const float*)d_in[2];
    const float* bmlp = (const float*)d_in[3];
    const float* g1   = (const float*)d_in[4];
    const float* be1  = (const float*)d_in[5];
    const float* Wres = (const float*)d_in[6];
    const float* g2   = (const float*)d_in[7];
    const float* be2  = (const float*)d_in[8];

    // workspace (~172 MiB of 256)
    char* ws = (char*)d_ws;
    u16*    Xb   = (u16*)ws;    ws += (size_t)16777216;   // (32768,256)
    u16*    XT   = (u16*)ws;    ws += (size_t)16777216;   // (B,256,4096)
    u16*    Vb   = (u16*)ws;    ws += (size_t)16777216;   // (32768,256)
    u16*    VT2  = (u16*)ws;    ws += (size_t)16777216;   // (B,256,4096)
    u16*    OUT  = (u16*)ws;    ws += (size_t)16777216;   // (32768,256)
    u16*    MLPo = (u16*)ws;    ws += (size_t)33554432;   // (32768,512)
    u16*    Tb   = (u16*)ws;    ws += (size_t)16777216;   // (32768,256)
    float*  ctxp = (float*)ws;  ws += (size_t)33554432;   // (B*16,256,256) fp32
    u16*    ctxb = (u16*)ws;    ws += (size_t)1048576;    // (B,256,256)
    float2* smst = (float2*)ws; ws += (size_t)262144;     // (32768) {0,sumexp}
    float2* lnst = (float2*)ws; ws += (size_t)262144;     // (32768) {mean,rstd}
    u16*    Wq_b = (u16*)ws;    ws += (size_t)131072;
    u16*    Wm_b = (u16*)ws;    ws += (size_t)524288;
    u16*    Wr_b = (u16*)ws;    ws += (size_t)524288;
    float*  sg   = (float*)ws;  ws += (size_t)1024;       // (256) sum g*Wres
    float*  br   = (float*)ws;  ws += (size_t)1024;       // (256) sum be*Wres
    u16*    xt   = MLPo;  // alias: xt dead before MLPo's first write

    // 0. weights fp32 -> bf16 (+ LN-fold prep for Wres) + zero softmax sums
    wconv_k<<<dim3(320), 256, 0, stream>>>(Wqkv, Wmlp, Wq_b, Wm_b);
    wresprep_k<<<dim3(64), 256, 0, stream>>>(Wres, g1, be1, Wr_b, sg, br);
    zerosm_k<<<dim3(128), 256, 0, stream>>>(smst);

    // 1. xt = transpose(x): per batch (256,4096) fp32 -> (4096,256) bf16
    transpose_k<float, u16><<<dim3(128, 8, 8), 256, 0, stream>>>(
        x, xt, 256, 4096, 256L * 4096, 4096L * 256);

    // 2. fused qkv: Xb = xt @ Wqkv^T, XT = Xb^T (per batch), smst.y = rowsum
    //    of exp(Xb)  [M=32768,N=256,K=256]
    gemm_bt<5, 0><<<dim3(2, 256, 1), 512, 0, stream>>>(
        xt, nullptr, nullptr, 256, 0, 0, 0, Wq_b, 256, 0, 0, 0, 256, 1,
        nullptr, Xb, 0, 0, 256, XT, nullptr, smst, nullptr, nullptr);

    const u16* VTcur = XT;
    const u16* Vcur  = Xb;

    for (int it = 0; it < 2; ++it) {
        // ctx split-K=16 partials
        gemm_bt<1, 0><<<dim3(2, 2, 128), 512, 0, stream>>>(
            VTcur, nullptr, nullptr, 4096, 0, 0, 0, XT, 4096,
            1048576, 1048576, 0, 256, 16,
            ctxp, nullptr, 65536, 0, 256, nullptr, nullptr, nullptr, nullptr, nullptr);
        ctxreduce_k<<<dim3(512), 256, 0, stream>>>(ctxp, ctxb);

        // OUT = softmax(Xb) @ ctxT^T  (exp in staging) [per batch 4096x256,K=256]
        gemm_bt<0, 1><<<dim3(2, 32, 8), 512, 0, stream>>>(
            Xb, nullptr, nullptr, 256, 0, 0, 0, ctxb, 256,
            1048576, 65536, 4096, 256, 1,
            nullptr, OUT, 0, 1048576, 256, nullptr, nullptr, smst, nullptr, nullptr);

        // MLPo = relu([OUT|Vcur] @ Wmlp^T + b)  [M=32768,N=512,K=512 split@256]
        gemm_bt<3, 3><<<dim3(4, 256, 1), 512, 0, stream>>>(
            OUT, Vcur, nullptr, 256, 256, 0, 256, Wm_b, 512, 0, 0, 0, 512, 1,
            nullptr, MLPo, 0, 0, 512, nullptr, bmlp, nullptr, nullptr, nullptr);

        // LN1024 stats
        stats1024_k<<<dim3(8192), 256, 0, stream>>>(OUT, Vcur, MLPo, lnst);

        // Tb = LN1024([OUT|Vcur|MLPo]) @ Wres^T + 2*Xb  [M=32768,N=256,K=1024]
        // LN folded into Wr_b/sg/br; applied in the epilogue.
        gemm_bt<4, 2><<<dim3(2, 256, 1), 512, 0, stream>>>(
            OUT, Vcur, MLPo, 256, 256, 512, 0, Wr_b, 1024, 0, 0, 0, 1024, 1,
            nullptr, Tb, 0, 0, 256, Xb, nullptr, lnst, sg, br);

        // LN256 + transpose fused
        if (it == 0) {
            ln256t_k<u16, true><<<dim3(1024), 256, 0, stream>>>(
                Tb, g2, be2, Vb, VT2);
            VTcur = VT2;
            Vcur  = Vb;
        } else {
            ln256t_k<float, false><<<dim3(1024), 256, 0, stream>>>(
                Tb, g2, be2, nullptr, (float*)d_out);
        }
    }
}

// Round 12
// 327.875 us; speedup vs baseline: 1.1364x; 1.0184x over previous
//
#include <hip/hip_runtime.h>
#include <cstdint>
#include <cstddef>

// IT_Fast_Attn: B=8, C=256, N=4096, 2 iterations. fp32 I/O, bf16 compute.
// Round 21 (base r20, champion 333.9us): bf16 ctx split-K partials.
//   ctx partial round-trip was 32MB fp32 written + 32MB re-read per iter
//   for a 2MB result. Partials now bf16 (16MB each way, -32MB/iter).
//   Precision: partial rounding RSS ~0.15 ~= existing final-bf16 ctx
//   rounding; absmax pinned at 0.03125 (terminal-rounding-dominated).
//   Also: zerosm folded into wresprep (-1 launch).
// r20 win confirmed T1: XCD swizzle -21.5us (partner-tile L2 reuse).
// Swizzle (LDS, rule #21 both-sides): global chunk (t&7)^(sRow&7), read
// chunk (h*4+q)^(mrow&7); phys chunk p of row r = logical p^(r&7).

using u16 = unsigned short;
using short8 = __attribute__((ext_vector_type(8))) short;
using bf16x8 = __attribute__((ext_vector_type(8))) __bf16;
using f32x4  = __attribute__((ext_vector_type(4))) float;
using i32x4  = __attribute__((ext_vector_type(4))) int;
using u16x4  = __attribute__((ext_vector_type(4))) u16;
using u16x8  = __attribute__((ext_vector_type(8))) u16;

__device__ __forceinline__ float b2f(u16 u) {
    union { unsigned u32; float f; } c; c.u32 = ((unsigned)u) << 16; return c.f;
}
__device__ __forceinline__ u16 f2b(float f) {
    union { float f; unsigned u; } c; c.f = f;
    unsigned r = c.u + 0x7FFFu + ((c.u >> 16) & 1u);
    return (u16)(r >> 16);
}
__device__ __forceinline__ void cvt(u16 a,  u16& o)   { o = a; }
__device__ __forceinline__ void cvt(float a, u16& o)  { o = f2b(a); }
__device__ __forceinline__ void cvt(float a, float& o){ o = a; }
__device__ __forceinline__ void cvt(u16 a,  float& o) { o = b2f(a); }

// async global->LDS, 16 B/lane; lds dest = wave-uniform base + lane*16.
__device__ __forceinline__ void glds16(const u16* g, short* l) {
    __builtin_amdgcn_global_load_lds(
        (const __attribute__((address_space(1))) void*)g,
        (__attribute__((address_space(3))) void*)l, 16, 0, 0);
}

// ---------------------------------------------------------------------------
// BT GEMM: C[row,col] = sum_k A[row,k] * B[col,k].  BM=BN=128, BK=64.
// 512 threads = 8 waves in 4x2; wave covers 32 rows x 64 cols; 16 MFMAs/iter
// (2 mi x 4 ni x 2 k-halves of 16x16x32 bf16). COL-fastest tile order +
// T1 XCD swizzle (contiguous tile chunk per XCD -> partner-tile L2 reuse).
// Staging: wave w DMAs rows [w*8, w*8+8) of each 64-row half via
// global_load_lds (lane l -> row w*8+(l>>3), phys chunk l&7, global chunk
// (l&7)^((l>>3)&7)).  LDS stride 64 shorts, XOR-swizzled chunks.
// TRF: 0 plain | 1 softmax exp(a)*(1/sum) from stats[].y (A reg-staged) |
//      2 three-source region split over A|A2|A3 | 3 two-source split.
// MODE: 0 store bf16 | 1 bf16 partial per ks-slice (outB) | 3 +bias,relu
//       | 4 epilogue LN-fold | 5 fused qkv: Xb + XT(via Xres ptr) +
//         per-row exp-sum atomics into stats[].y.
// ---------------------------------------------------------------------------
template<int MODE, int TRF>
__global__ __launch_bounds__(512)
void gemm_bt(const u16* __restrict__ A, const u16* __restrict__ A2,
             const u16* __restrict__ A3,
             int lda, int lda2, int lda3, int kSplit,
             const u16* __restrict__ B, int ldb, long strA, long strB,
             int statStride, int kChunk, int nKsplit,
             float* __restrict__ outF, u16* __restrict__ outB,
             long sOF, long sOB, int ldo,
             const u16* __restrict__ Xres,
             const float* __restrict__ bias,
             const float2* __restrict__ stats,
             const float* __restrict__ g, const float* __restrict__ be)
{
    __shared__ short lsA[128 * 64];
    __shared__ short lsB[128 * 64];

    // T1: bijective XCD swizzle (every grid here has nwg % 8 == 0)
    const unsigned gx = gridDim.x, gy = gridDim.y;
    const unsigned nwg = gx * gy * gridDim.z;
    unsigned lin = blockIdx.x + gx * (blockIdx.y + gy * blockIdx.z);
    lin = (lin & 7u) * (nwg >> 3) + (lin >> 3);
    const unsigned sbx = lin % gx;
    const unsigned rest = lin / gx;
    const unsigned sby = rest % gy;
    const unsigned sbz = rest / gy;

    const int bz    = (int)sbz;
    const int batch = bz / nKsplit;
    const int ks    = bz - batch * nKsplit;
    const u16* Ab = A + (size_t)batch * strA;
    const u16* Bb = B + (size_t)batch * strB;
    const int colBase = (int)sbx * 128;   // col-fastest tile order
    const int rowBase = (int)sby * 128;
    const int k0 = ks * kChunk;
    const int k1 = k0 + kChunk;

    const int t    = threadIdx.x;
    const int sRow = t >> 3;                         // 0..63
    const int sKl  = (t & 7) << 3;                   // linear lds chunk (elems)
    const int sKg  = (((t & 7) ^ (sRow & 7)) << 3);  // swizzled global chunk

    const int lane = t & 63;
    const int w    = t >> 6;           // 0..7
    const int wr   = (w >> 1) * 32;    // wave row base
    const int wc   = (w & 1) * 64;     // wave col base
    const int mrow = lane & 15;
    const int q    = lane >> 4;

    // wave-uniform LDS DMA destinations (rows w*8..w*8+7 of each half)
    short* ldA0 = &lsA[w * 512];
    short* ldA1 = &lsA[4096 + w * 512];
    short* ldB0 = &lsB[w * 512];
    short* ldB1 = &lsB[4096 + w * 512];

    float2 st0 = {0.f, 0.f}, st1 = {0.f, 0.f};
    if (TRF == 1) {
        const int sb = batch * statStride + rowBase;
        const float2 t0 = stats[sb + sRow];
        const float2 t1 = stats[sb + sRow + 64];
        st0 = make_float2(0.f, 1.f / t0.y);   // y holds accumulated sum(exp)
        st1 = make_float2(0.f, 1.f / t1.y);
    }

    // per-lane global A pointer for window base kn (region from kn; the
    // swizzled chunk sKg stays inside [kn, kn+64))
    auto aPtr = [&](int rloc, int kn) -> const u16* {
        const int arow = rowBase + rloc + sRow;
        if (TRF == 2) {
            if (kn < 256)      return A  + (size_t)arow * lda  + kn + sKg;
            else if (kn < 512) return A2 + (size_t)arow * lda2 + (kn - 256) + sKg;
            else               return A3 + (size_t)arow * lda3 + (kn - 512) + sKg;
        } else if (TRF == 3) {
            if (kn < kSplit)   return Ab + (size_t)arow * lda + kn + sKg;
            return A2 + (size_t)arow * lda2 + (kn - kSplit) + sKg;
        }
        return Ab + (size_t)arow * lda + kn + sKg;
    };
    // TRF==1 reg path: load swizzled global chunk, transform (row-only stats,
    // safe under chunk permutation), ds_write to the LINEAR slot.
    auto loadX = [&](int rloc, int kn, float2 st) -> i32x4 {
        const int arow = rowBase + rloc + sRow;
        i32x4 raw = *(const i32x4*)(Ab + (size_t)arow * lda + kn + sKg);
        short8 h = __builtin_bit_cast(short8, raw);
        short8 o;
#pragma unroll
        for (int i = 0; i < 8; i++) {
            float v = b2f((u16)h[i]);
            v = __expf(v - st.x) * st.y;
            o[i] = (short)f2b(v);
        }
        return __builtin_bit_cast(i32x4, o);
    };

    const f32x4 fzero = {0.f, 0.f, 0.f, 0.f};
    f32x4 acc[2][4];
#pragma unroll
    for (int i = 0; i < 2; i++)
#pragma unroll
        for (int j = 0; j < 4; j++) acc[i][j] = fzero;

    const u16* pB0 = Bb + (size_t)(colBase + sRow) * ldb + sKg;
    const u16* pB1 = pB0 + (size_t)64 * ldb;
    const u16* pA0 = nullptr; const u16* pA1 = nullptr;
    if (TRF == 0) {
        pA0 = Ab + (size_t)(rowBase + sRow) * lda + sKg;
        pA1 = pA0 + (size_t)64 * lda;
    }

    // swizzled read chunk offsets (elems): phys chunk = (h*4+q)^(mrow&7)
    const int rsw = mrow & 7;
    const int kc0 = (((0 * 4 + q) ^ rsw) << 3);
    const int kc1 = (((1 * 4 + q) ^ rsw) << 3);

    i32x4 a0, a1;
    if (TRF == 1) {
        a0 = loadX(0,  k0, st0);
        a1 = loadX(64, k0, st1);
    }

    for (int kk = k0; kk < k1; kk += 64) {
        if (TRF == 1) {
            *(i32x4*)&lsA[sRow * 64 + sKl]        = a0;
            *(i32x4*)&lsA[(sRow + 64) * 64 + sKl] = a1;
        } else if (TRF == 0) {
            glds16(pA0 + kk, ldA0);
            glds16(pA1 + kk, ldA1);
        } else {
            glds16(aPtr(0,  kk), ldA0);
            glds16(aPtr(64, kk), ldA1);
        }
        glds16(pB0 + kk, ldB0);
        glds16(pB1 + kk, ldB1);
        __syncthreads();
        const int kn = kk + 64;
        if (TRF == 1 && kn < k1) {
            a0 = loadX(0,  kn, st0);
            a1 = loadX(64, kn, st1);
        }
#pragma unroll
        for (int h = 0; h < 2; h++) {
            const int kc = h ? kc1 : kc0;
            bf16x8 af[2], bfr[4];
#pragma unroll
            for (int mi = 0; mi < 2; mi++)
                af[mi] = __builtin_bit_cast(bf16x8,
                    *(const short8*)&lsA[(wr + mi * 16 + mrow) * 64 + kc]);
#pragma unroll
            for (int ni = 0; ni < 4; ni++)
                bfr[ni] = __builtin_bit_cast(bf16x8,
                    *(const short8*)&lsB[(wc + ni * 16 + mrow) * 64 + kc]);
#pragma unroll
            for (int mi = 0; mi < 2; mi++)
#pragma unroll
                for (int ni = 0; ni < 4; ni++)
                    acc[mi][ni] = __builtin_amdgcn_mfma_f32_16x16x32_bf16(
                        af[mi], bfr[ni], acc[mi][ni], 0, 0, 0);
        }
        __syncthreads();
    }

    if (MODE == 5) {
        // fused qkv epilogue: Xb (scalar), XT (u16x4: 4 consecutive rows =
        // 4 consecutive n at fixed col), per-row sum(exp) -> atomicAdd.
        u16* XT = const_cast<u16*>(Xres);
        float2* sm = const_cast<float2*>(stats);
        float rsum[2][4] = {{0.f,0.f,0.f,0.f},{0.f,0.f,0.f,0.f}};
#pragma unroll
        for (int mi = 0; mi < 2; mi++) {
#pragma unroll
            for (int ni = 0; ni < 4; ni++) {
                const int col  = colBase + wc + ni * 16 + mrow;
                const int row0 = rowBase + wr + mi * 16 + q * 4;
                u16x4 hv;
#pragma unroll
                for (int r = 0; r < 4; r++) {
                    const u16 h = f2b(acc[mi][ni][r]);
                    hv[r] = h;
                    outB[(size_t)(row0 + r) * ldo + col] = h;
                    rsum[mi][r] += __expf(b2f(h));
                }
                *(u16x4*)(XT + (size_t)(row0 >> 12) * 1048576
                             + (size_t)col * 4096 + (row0 & 4095)) = hv;
            }
        }
#pragma unroll
        for (int mi = 0; mi < 2; mi++)
#pragma unroll
            for (int r = 0; r < 4; r++) {
                float s = rsum[mi][r];
                s += __shfl_xor(s, 1); s += __shfl_xor(s, 2);
                s += __shfl_xor(s, 4); s += __shfl_xor(s, 8);
                if (mrow == 0)
                    atomicAdd(&sm[rowBase + wr + mi * 16 + q * 4 + r].y, s);
            }
        return;
    }

    // epilogue: lane holds D[row = q*4+r][col = mrow] per 16x16 tile
#pragma unroll
    for (int mi = 0; mi < 2; mi++) {
#pragma unroll
        for (int ni = 0; ni < 4; ni++) {
            const int col = colBase + wc + ni * 16 + mrow;
#pragma unroll
            for (int r = 0; r < 4; r++) {
                const int row = rowBase + wr + mi * 16 + q * 4 + r;
                float v = acc[mi][ni][r];
                if (MODE == 0) {
                    outB[(size_t)batch * sOB + (size_t)row * ldo + col] = f2b(v);
                } else if (MODE == 1) {
                    // bf16 split-K partial for slice (batch, ks)
                    outB[((size_t)batch * nKsplit + ks) * sOB
                         + (size_t)row * ldo + col] = f2b(v);
                } else if (MODE == 3) {
                    v += bias[col];
                    v = v > 0.f ? v : 0.f;
                    outB[(size_t)row * ldo + col] = f2b(v);
                } else if (MODE == 4) {
                    // LN-fold: rstd*(acc - mu*sg[col]) + br[col] + 2*Xres
                    const float2 ln = stats[row];   // {mean, rstd}
                    v = ln.y * (v - ln.x * g[col]) + be[col]
                        + 2.f * b2f(Xres[(size_t)row * 256 + col]);
                    outB[(size_t)row * ldo + col] = f2b(v);
                }
            }
        }
    }
}

// ---------------------------------------------------------------------------
// Transpose (R x Cc) -> (Cc x R) per batch, with dtype conversion.
// ---------------------------------------------------------------------------
template<typename TIN, typename TOUT>
__global__ __launch_bounds__(256)
void transpose_k(const TIN* __restrict__ in, TOUT* __restrict__ out,
                 int R, int Cc, long sIn, long sOut)
{
    __shared__ TOUT tile[32][33];
    const int b = blockIdx.z;
    const TIN* ib = in + (size_t)b * sIn;
    TOUT* ob = out + (size_t)b * sOut;
    const int c0 = blockIdx.x * 32, r0 = blockIdx.y * 32;
    const int tx = threadIdx.x & 31, ty = threadIdx.x >> 5;
#pragma unroll
    for (int i = 0; i < 32; i += 8)
        cvt(ib[(size_t)(r0 + ty + i) * Cc + c0 + tx], tile[ty + i][tx]);
    __syncthreads();
#pragma unroll
    for (int i = 0; i < 32; i += 8)
        ob[(size_t)(c0 + ty + i) * R + r0 + tx] = tile[tx][ty + i];
}

// Per-row LN stats of virtual row [OUT(256)|V(256)|MLPo(512)]: {mean, rstd}.
__global__ __launch_bounds__(256)
void stats1024_k(const u16* __restrict__ OUT, const u16* __restrict__ V,
                 const u16* __restrict__ MLPo, float2* __restrict__ st)
{
    const int wave = threadIdx.x >> 6, lane = threadIdx.x & 63;
    const size_t row = (size_t)blockIdx.x * 4 + wave;
    const int c = lane * 16;
    const u16* src;
    if (c < 256)       src = OUT  + row * 256 + c;
    else if (c < 512)  src = V    + row * 256 + (c - 256);
    else               src = MLPo + row * 512 + (c - 512);
    short8 r0 = *(const short8*)(src);
    short8 r1 = *(const short8*)(src + 8);
    float s = 0.f, s2 = 0.f;
#pragma unroll
    for (int i = 0; i < 8; i++) {
        const float a = b2f((u16)r0[i]), b = b2f((u16)r1[i]);
        s += a + b; s2 += a * a + b * b;
    }
    for (int o = 32; o > 0; o >>= 1) { s += __shfl_xor(s, o); s2 += __shfl_xor(s2, o); }
    const float mean = s * (1.f / 1024.f);
    const float var  = s2 * (1.f / 1024.f) - mean * mean;
    if (lane == 0) st[row] = make_float2(mean, rsqrtf(var + 1e-5f));
}

// ---------------------------------------------------------------------------
// Fused LN256 + transpose (unchanged from r5).
// ---------------------------------------------------------------------------
template<typename OUTT, bool WRITE_VB>
__global__ __launch_bounds__(256)
void ln256t_k(const u16* __restrict__ Tb, const float* __restrict__ g,
              const float* __restrict__ be, u16* __restrict__ Vb,
              OUTT* __restrict__ outT)
{
    constexpr int STRIDE = (sizeof(OUTT) == 2) ? 266 : 261;
    __shared__ OUTT tile[32 * STRIDE];
    const int wid = threadIdx.x >> 6, lane = threadIdx.x & 63;
    const int bx = blockIdx.x;
    const size_t r0 = (size_t)bx * 32;
    const int b  = bx >> 7;
    const int n0 = (bx & 127) * 32;

#pragma unroll
    for (int j = 0; j < 8; j++) {
        const int lr = wid * 8 + j;
        const size_t row = r0 + lr;
        const u16x4 tb = *(const u16x4*)(Tb + row * 256 + lane * 4);
        const float x0 = b2f(tb.x), x1 = b2f(tb.y), x2 = b2f(tb.z), x3 = b2f(tb.w);
        float s  = x0 + x1 + x2 + x3;
        float s2 = x0 * x0 + x1 * x1 + x2 * x2 + x3 * x3;
        for (int o = 32; o > 0; o >>= 1) { s += __shfl_xor(s, o); s2 += __shfl_xor(s2, o); }
        const float mean = s * (1.f / 256.f);
        const float var  = s2 * (1.f / 256.f) - mean * mean;
        const float rstd = rsqrtf(var + 1e-5f);
        const int c = lane * 4;
        float4 ov = { (x0 - mean) * rstd * g[c + 0] + be[c + 0],
                      (x1 - mean) * rstd * g[c + 1] + be[c + 1],
                      (x2 - mean) * rstd * g[c + 2] + be[c + 2],
                      (x3 - mean) * rstd * g[c + 3] + be[c + 3] };
        if (WRITE_VB) {
            u16x4 vb = { f2b(ov.x), f2b(ov.y), f2b(ov.z), f2b(ov.w) };
            *(u16x4*)(Vb + row * 256 + c) = vb;
        }
        OUTT* tl = &tile[lr * STRIDE + c];
        cvt(ov.x, tl[0]); cvt(ov.y, tl[1]); cvt(ov.z, tl[2]); cvt(ov.w, tl[3]);
    }
    __syncthreads();

    const int c = threadIdx.x;
    OUTT* dst = outT + ((size_t)b * 256 + c) * 4096 + n0;
    if (sizeof(OUTT) == 2) {
#pragma unroll
        for (int k = 0; k < 4; k++) {
            u16x8 v;
#pragma unroll
            for (int i = 0; i < 8; i++) v[i] = *(const u16*)&tile[(k * 8 + i) * STRIDE + c];
            *(u16x8*)((u16*)dst + k * 8) = v;
        }
    } else {
#pragma unroll
        for (int k = 0; k < 8; k++) {
            float4 v;
            v.x = *(const float*)&tile[(k * 4 + 0) * STRIDE + c];
            v.y = *(const float*)&tile[(k * 4 + 1) * STRIDE + c];
            v.z = *(const float*)&tile[(k * 4 + 2) * STRIDE + c];
            v.w = *(const float*)&tile[(k * 4 + 3) * STRIDE + c];
            *(float4*)((float*)dst + k * 4) = v;
        }
    }
}

// Reduce 16 bf16 split-K partial ctx buffers -> bf16 (fp32 accumulate).
__global__ __launch_bounds__(256)
void ctxreduce_k(const u16* __restrict__ ctxp, u16* __restrict__ ctxb)
{
    const int i = blockIdx.x * 256 + threadIdx.x;      // 131072 x u16x4 groups
    const int batch  = i >> 14;
    const int within = i & 16383;
    const u16x4* src = (const u16x4*)ctxp + (size_t)batch * 16 * 16384 + within;
    float4 s = {0.f, 0.f, 0.f, 0.f};
#pragma unroll
    for (int ks = 0; ks < 16; ks++) {
        const u16x4 v = src[(size_t)ks * 16384];
        s.x += b2f(v.x); s.y += b2f(v.y); s.z += b2f(v.z); s.w += b2f(v.w);
    }
    u16x4 o = { f2b(s.x), f2b(s.y), f2b(s.z), f2b(s.w) };
    ((u16x4*)ctxb)[i] = o;
}

// Convert Wqkv and Wmlp fp32->bf16 in one launch (Wres handled by wresprep_k).
__global__ __launch_bounds__(256)
void wconv_k(const float* __restrict__ Wq, const float* __restrict__ Wm,
             u16* __restrict__ oq, u16* __restrict__ om)
{
    const int i = blockIdx.x * 256 + threadIdx.x;
    const float* src; u16* dst; int j;
    if (i < 16384) { src = Wq; dst = oq; j = i; }
    else           { src = Wm; dst = om; j = i - 16384; }
    const float4 v = ((const float4*)src)[j];
    u16x4 o = { f2b(v.x), f2b(v.y), f2b(v.z), f2b(v.w) };
    ((u16x4*)dst)[j] = o;
}

// LN-fold prep: Wr_b[c,k] = bf16(Wres[c,k]*g1[k]);
// sg[c] = sum_k g1[k]*Wres[c,k];  br[c] = sum_k be1[k]*Wres[c,k].
// Also zeroes smst (32768 float2): thread i zeroes smst[2i], smst[2i+1].
__global__ __launch_bounds__(256)
void wresprep_k(const float* __restrict__ Wres, const float* __restrict__ g1,
                const float* __restrict__ be1, u16* __restrict__ Wr_b,
                float* __restrict__ sg, float* __restrict__ br,
                float2* __restrict__ smst)
{
    const int tid = blockIdx.x * 256 + threadIdx.x;    // 0..16383
    smst[tid * 2]     = make_float2(0.f, 0.f);
    smst[tid * 2 + 1] = make_float2(0.f, 0.f);

    const int wv = threadIdx.x >> 6, lane = threadIdx.x & 63;
    const int row = blockIdx.x * 4 + wv;
    const float* src = Wres + (size_t)row * 1024;
    float s = 0.f, b = 0.f;
#pragma unroll
    for (int j = 0; j < 4; j++) {
        const int c = j * 256 + lane * 4;
        const float4 w  = *(const float4*)(src + c);
        const float4 gg = *(const float4*)(g1 + c);
        const float4 bb = *(const float4*)(be1 + c);
        const float4 wg = { w.x * gg.x, w.y * gg.y, w.z * gg.z, w.w * gg.w };
        u16x4 o = { f2b(wg.x), f2b(wg.y), f2b(wg.z), f2b(wg.w) };
        *(u16x4*)(Wr_b + (size_t)row * 1024 + c) = o;
        s += wg.x + wg.y + wg.z + wg.w;
        b += w.x * bb.x + w.y * bb.y + w.z * bb.z + w.w * bb.w;
    }
    for (int o = 32; o > 0; o >>= 1) { s += __shfl_xor(s, o); b += __shfl_xor(b, o); }
    if (lane == 0) { sg[row] = s; br[row] = b; }
}

extern "C" void kernel_launch(void* const* d_in, const int* in_sizes, int n_in,
                              void* d_out, int out_size, void* d_ws, size_t ws_size,
                              hipStream_t stream)
{
    (void)in_sizes; (void)n_in; (void)out_size; (void)ws_size;
    const float* x    = (const float*)d_in[0];
    const float* Wqkv = (const float*)d_in[1];
    const float* Wmlp = (const float*)d_in[2];
    const float* bmlp = (const float*)d_in[3];
    const float* g1   = (const float*)d_in[4];
    const float* be1  = (const float*)d_in[5];
    const float* Wres = (const float*)d_in[6];
    const float* g2   = (const float*)d_in[7];
    const float* be2  = (const float*)d_in[8];

    // workspace (~156 MiB of 256)
    char* ws = (char*)d_ws;
    u16*    Xb   = (u16*)ws;    ws += (size_t)16777216;   // (32768,256)
    u16*    XT   = (u16*)ws;    ws += (size_t)16777216;   // (B,256,4096)
    u16*    Vb   = (u16*)ws;    ws += (size_t)16777216;   // (32768,256)
    u16*    VT2  = (u16*)ws;    ws += (size_t)16777216;   // (B,256,4096)
    u16*    OUT  = (u16*)ws;    ws += (size_t)16777216;   // (32768,256)
    u16*    MLPo = (u16*)ws;    ws += (size_t)33554432;   // (32768,512)
    u16*    Tb   = (u16*)ws;    ws += (size_t)16777216;   // (32768,256)
    u16*    ctxp = (u16*)ws;    ws += (size_t)16777216;   // (B*16,256,256) bf16
    u16*    ctxb = (u16*)ws;    ws += (size_t)1048576;    // (B,256,256)
    float2* smst = (float2*)ws; ws += (size_t)262144;     // (32768) {0,sumexp}
    float2* lnst = (float2*)ws; ws += (size_t)262144;     // (32768) {mean,rstd}
    u16*    Wq_b = (u16*)ws;    ws += (size_t)131072;
    u16*    Wm_b = (u16*)ws;    ws += (size_t)524288;
    u16*    Wr_b = (u16*)ws;    ws += (size_t)524288;
    float*  sg   = (float*)ws;  ws += (size_t)1024;       // (256) sum g*Wres
    float*  br   = (float*)ws;  ws += (size_t)1024;       // (256) sum be*Wres
    u16*    xt   = MLPo;  // alias: xt dead before MLPo's first write

    // 0. weights fp32 -> bf16 (+ LN-fold prep for Wres, zeroes smst)
    wconv_k<<<dim3(320), 256, 0, stream>>>(Wqkv, Wmlp, Wq_b, Wm_b);
    wresprep_k<<<dim3(64), 256, 0, stream>>>(Wres, g1, be1, Wr_b, sg, br, smst);

    // 1. xt = transpose(x): per batch (256,4096) fp32 -> (4096,256) bf16
    transpose_k<float, u16><<<dim3(128, 8, 8), 256, 0, stream>>>(
        x, xt, 256, 4096, 256L * 4096, 4096L * 256);

    // 2. fused qkv: Xb = xt @ Wqkv^T, XT = Xb^T (per batch), smst.y = rowsum
    //    of exp(Xb)  [M=32768,N=256,K=256]
    gemm_bt<5, 0><<<dim3(2, 256, 1), 512, 0, stream>>>(
        xt, nullptr, nullptr, 256, 0, 0, 0, Wq_b, 256, 0, 0, 0, 256, 1,
        nullptr, Xb, 0, 0, 256, XT, nullptr, smst, nullptr, nullptr);

    const u16* VTcur = XT;
    const u16* Vcur  = Xb;

    for (int it = 0; it < 2; ++it) {
        // ctx split-K=16 bf16 partials
        gemm_bt<1, 0><<<dim3(2, 2, 128), 512, 0, stream>>>(
            VTcur, nullptr, nullptr, 4096, 0, 0, 0, XT, 4096,
            1048576, 1048576, 0, 256, 16,
            nullptr, ctxp, 0, 65536, 256, nullptr, nullptr, nullptr, nullptr, nullptr);
        ctxreduce_k<<<dim3(512), 256, 0, stream>>>(ctxp, ctxb);

        // OUT = softmax(Xb) @ ctxT^T  (exp in staging) [per batch 4096x256,K=256]
        gemm_bt<0, 1><<<dim3(2, 32, 8), 512, 0, stream>>>(
            Xb, nullptr, nullptr, 256, 0, 0, 0, ctxb, 256,
            1048576, 65536, 4096, 256, 1,
            nullptr, OUT, 0, 1048576, 256, nullptr, nullptr, smst, nullptr, nullptr);

        // MLPo = relu([OUT|Vcur] @ Wmlp^T + b)  [M=32768,N=512,K=512 split@256]
        gemm_bt<3, 3><<<dim3(4, 256, 1), 512, 0, stream>>>(
            OUT, Vcur, nullptr, 256, 256, 0, 256, Wm_b, 512, 0, 0, 0, 512, 1,
            nullptr, MLPo, 0, 0, 512, nullptr, bmlp, nullptr, nullptr, nullptr);

        // LN1024 stats
        stats1024_k<<<dim3(8192), 256, 0, stream>>>(OUT, Vcur, MLPo, lnst);

        // Tb = LN1024([OUT|Vcur|MLPo]) @ Wres^T + 2*Xb  [M=32768,N=256,K=1024]
        // LN folded into Wr_b/sg/br; applied in the epilogue.
        gemm_bt<4, 2><<<dim3(2, 256, 1), 512, 0, stream>>>(
            OUT, Vcur, MLPo, 256, 256, 512, 0, Wr_b, 1024, 0, 0, 0, 1024, 1,
            nullptr, Tb, 0, 0, 256, Xb, nullptr, lnst, sg, br);

        // LN256 + transpose fused
        if (it == 0) {
            ln256t_k<u16, true><<<dim3(1024), 256, 0, stream>>>(
                Tb, g2, be2, Vb, VT2);
            VTcur = VT2;
            Vcur  = Vb;
        } else {
            ln256t_k<float, false><<<dim3(1024), 256, 0, stream>>>(
                Tb, g2, be2, nullptr, (float*)d_out);
        }
    }
}

// Round 13
// 326.381 us; speedup vs baseline: 1.1416x; 1.0046x over previous
//
#include <hip/hip_runtime.h>
#include <cstdint>
#include <cstddef>

// IT_Fast_Attn: B=8, C=256, N=4096, 2 iterations. fp32 I/O, bf16 compute.
// Round 22 (base r21, champion 327.9us): in-GEMM LN1024 stats.
//   stats1024_k re-read 64MB/iter of just-written OUT|V|MLPo. The res GEMM
//   (MODE 4, grid (2,256)) already stages the FULL K=1024 of its 128 rows
//   through lsA -> each block computes row {sum,sumsq} itself:
//   per K-step ds_read-back of own chunks (lane-linear, conflict-free) +
//   fp32 accumulate; end: 3-step shfl_xor over 8 chunk-threads -> lstat[128]
//   in LDS -> epilogue mean/rstd from LDS (broadcast reads). No atomics,
//   no extra pass (r18's failed approach), both col-blocks compute
//   identical stats redundantly. stats1024_k deleted (-2 dispatches,
//   -128MB reads).
// r20/r21 wins: T1 XCD swizzle (-21.5us), bf16 ctx partials (-6us).
// Swizzle (LDS, rule #21 both-sides): global chunk (t&7)^(sRow&7), read
// chunk (h*4+q)^(mrow&7); phys chunk p of row r = logical p^(r&7).

using u16 = unsigned short;
using short8 = __attribute__((ext_vector_type(8))) short;
using bf16x8 = __attribute__((ext_vector_type(8))) __bf16;
using f32x4  = __attribute__((ext_vector_type(4))) float;
using i32x4  = __attribute__((ext_vector_type(4))) int;
using u16x4  = __attribute__((ext_vector_type(4))) u16;
using u16x8  = __attribute__((ext_vector_type(8))) u16;

__device__ __forceinline__ float b2f(u16 u) {
    union { unsigned u32; float f; } c; c.u32 = ((unsigned)u) << 16; return c.f;
}
__device__ __forceinline__ u16 f2b(float f) {
    union { float f; unsigned u; } c; c.f = f;
    unsigned r = c.u + 0x7FFFu + ((c.u >> 16) & 1u);
    return (u16)(r >> 16);
}
__device__ __forceinline__ void cvt(u16 a,  u16& o)   { o = a; }
__device__ __forceinline__ void cvt(float a, u16& o)  { o = f2b(a); }
__device__ __forceinline__ void cvt(float a, float& o){ o = a; }
__device__ __forceinline__ void cvt(u16 a,  float& o) { o = b2f(a); }

// async global->LDS, 16 B/lane; lds dest = wave-uniform base + lane*16.
__device__ __forceinline__ void glds16(const u16* g, short* l) {
    __builtin_amdgcn_global_load_lds(
        (const __attribute__((address_space(1))) void*)g,
        (__attribute__((address_space(3))) void*)l, 16, 0, 0);
}

// ---------------------------------------------------------------------------
// BT GEMM: C[row,col] = sum_k A[row,k] * B[col,k].  BM=BN=128, BK=64.
// 512 threads = 8 waves in 4x2; wave covers 32 rows x 64 cols; 16 MFMAs/iter
// (2 mi x 4 ni x 2 k-halves of 16x16x32 bf16). COL-fastest tile order +
// T1 XCD swizzle (contiguous tile chunk per XCD -> partner-tile L2 reuse).
// Staging: wave w DMAs rows [w*8, w*8+8) of each 64-row half via
// global_load_lds (lane l -> row w*8+(l>>3), phys chunk l&7, global chunk
// (l&7)^((l>>3)&7)).  LDS stride 64 shorts, XOR-swizzled chunks.
// TRF: 0 plain | 1 softmax exp(a)*(1/sum) from stats[].y (A reg-staged) |
//      2 three-source region split over A|A2|A3 | 3 two-source split.
// MODE: 0 store bf16 | 1 bf16 partial per ks-slice (outB) | 3 +bias,relu
//       | 4 LN-fold epilogue with IN-KERNEL row stats (lstat from staged A)
//       | 5 fused qkv: Xb + XT(via Xres ptr) + exp-sum atomics (stats.y).
// ---------------------------------------------------------------------------
template<int MODE, int TRF>
__global__ __launch_bounds__(512)
void gemm_bt(const u16* __restrict__ A, const u16* __restrict__ A2,
             const u16* __restrict__ A3,
             int lda, int lda2, int lda3, int kSplit,
             const u16* __restrict__ B, int ldb, long strA, long strB,
             int statStride, int kChunk, int nKsplit,
             float* __restrict__ outF, u16* __restrict__ outB,
             long sOF, long sOB, int ldo,
             const u16* __restrict__ Xres,
             const float* __restrict__ bias,
             const float2* __restrict__ stats,
             const float* __restrict__ g, const float* __restrict__ be)
{
    __shared__ short lsA[128 * 64];
    __shared__ short lsB[128 * 64];
    __shared__ float2 lstat[128];   // MODE==4: per-row {sum, sumsq}

    // T1: bijective XCD swizzle (every grid here has nwg % 8 == 0)
    const unsigned gx = gridDim.x, gy = gridDim.y;
    const unsigned nwg = gx * gy * gridDim.z;
    unsigned lin = blockIdx.x + gx * (blockIdx.y + gy * blockIdx.z);
    lin = (lin & 7u) * (nwg >> 3) + (lin >> 3);
    const unsigned sbx = lin % gx;
    const unsigned rest = lin / gx;
    const unsigned sby = rest % gy;
    const unsigned sbz = rest / gy;

    const int bz    = (int)sbz;
    const int batch = bz / nKsplit;
    const int ks    = bz - batch * nKsplit;
    const u16* Ab = A + (size_t)batch * strA;
    const u16* Bb = B + (size_t)batch * strB;
    const int colBase = (int)sbx * 128;   // col-fastest tile order
    const int rowBase = (int)sby * 128;
    const int k0 = ks * kChunk;
    const int k1 = k0 + kChunk;

    const int t    = threadIdx.x;
    const int sRow = t >> 3;                         // 0..63
    const int sKl  = (t & 7) << 3;                   // linear lds chunk (elems)
    const int sKg  = (((t & 7) ^ (sRow & 7)) << 3);  // swizzled global chunk

    const int lane = t & 63;
    const int w    = t >> 6;           // 0..7
    const int wr   = (w >> 1) * 32;    // wave row base
    const int wc   = (w & 1) * 64;     // wave col base
    const int mrow = lane & 15;
    const int q    = lane >> 4;

    // wave-uniform LDS DMA destinations (rows w*8..w*8+7 of each half)
    short* ldA0 = &lsA[w * 512];
    short* ldA1 = &lsA[4096 + w * 512];
    short* ldB0 = &lsB[w * 512];
    short* ldB1 = &lsB[4096 + w * 512];

    float2 st0 = {0.f, 0.f}, st1 = {0.f, 0.f};
    if (TRF == 1) {
        const int sb = batch * statStride + rowBase;
        const float2 t0 = stats[sb + sRow];
        const float2 t1 = stats[sb + sRow + 64];
        st0 = make_float2(0.f, 1.f / t0.y);   // y holds accumulated sum(exp)
        st1 = make_float2(0.f, 1.f / t1.y);
    }

    // per-lane global A pointer for window base kn (region from kn; the
    // swizzled chunk sKg stays inside [kn, kn+64))
    auto aPtr = [&](int rloc, int kn) -> const u16* {
        const int arow = rowBase + rloc + sRow;
        if (TRF == 2) {
            if (kn < 256)      return A  + (size_t)arow * lda  + kn + sKg;
            else if (kn < 512) return A2 + (size_t)arow * lda2 + (kn - 256) + sKg;
            else               return A3 + (size_t)arow * lda3 + (kn - 512) + sKg;
        } else if (TRF == 3) {
            if (kn < kSplit)   return Ab + (size_t)arow * lda + kn + sKg;
            return A2 + (size_t)arow * lda2 + (kn - kSplit) + sKg;
        }
        return Ab + (size_t)arow * lda + kn + sKg;
    };
    // TRF==1 reg path: load swizzled global chunk, transform (row-only stats,
    // safe under chunk permutation), ds_write to the LINEAR slot.
    auto loadX = [&](int rloc, int kn, float2 st) -> i32x4 {
        const int arow = rowBase + rloc + sRow;
        i32x4 raw = *(const i32x4*)(Ab + (size_t)arow * lda + kn + sKg);
        short8 h = __builtin_bit_cast(short8, raw);
        short8 o;
#pragma unroll
        for (int i = 0; i < 8; i++) {
            float v = b2f((u16)h[i]);
            v = __expf(v - st.x) * st.y;
            o[i] = (short)f2b(v);
        }
        return __builtin_bit_cast(i32x4, o);
    };

    const f32x4 fzero = {0.f, 0.f, 0.f, 0.f};
    f32x4 acc[2][4];
#pragma unroll
    for (int i = 0; i < 2; i++)
#pragma unroll
        for (int j = 0; j < 4; j++) acc[i][j] = fzero;

    const u16* pB0 = Bb + (size_t)(colBase + sRow) * ldb + sKg;
    const u16* pB1 = pB0 + (size_t)64 * ldb;
    const u16* pA0 = nullptr; const u16* pA1 = nullptr;
    if (TRF == 0) {
        pA0 = Ab + (size_t)(rowBase + sRow) * lda + sKg;
        pA1 = pA0 + (size_t)64 * lda;
    }

    // swizzled read chunk offsets (elems): phys chunk = (h*4+q)^(mrow&7)
    const int rsw = mrow & 7;
    const int kc0 = (((0 * 4 + q) ^ rsw) << 3);
    const int kc1 = (((1 * 4 + q) ^ rsw) << 3);

    // MODE==4: per-thread row-stat accumulators (rows sRow, sRow+64)
    float stA = 0.f, stA2 = 0.f, stB = 0.f, stB2 = 0.f;

    i32x4 a0, a1;
    if (TRF == 1) {
        a0 = loadX(0,  k0, st0);
        a1 = loadX(64, k0, st1);
    }

    for (int kk = k0; kk < k1; kk += 64) {
        if (TRF == 1) {
            *(i32x4*)&lsA[sRow * 64 + sKl]        = a0;
            *(i32x4*)&lsA[(sRow + 64) * 64 + sKl] = a1;
        } else if (TRF == 0) {
            glds16(pA0 + kk, ldA0);
            glds16(pA1 + kk, ldA1);
        } else {
            glds16(aPtr(0,  kk), ldA0);
            glds16(aPtr(64, kk), ldA1);
        }
        glds16(pB0 + kk, ldB0);
        glds16(pB1 + kk, ldB1);
        __syncthreads();
        const int kn = kk + 64;
        if (TRF == 1 && kn < k1) {
            a0 = loadX(0,  kn, st0);
            a1 = loadX(64, kn, st1);
        }
        if (MODE == 4) {
            // read back own chunks (lane-linear, conflict-free); sums are
            // chunk-permutation-invariant so the XOR swizzle is irrelevant.
            short8 c0 = *(const short8*)&lsA[sRow * 64 + sKl];
            short8 c1 = *(const short8*)&lsA[(sRow + 64) * 64 + sKl];
#pragma unroll
            for (int i = 0; i < 8; i++) {
                const float v0 = b2f((u16)c0[i]);
                const float v1 = b2f((u16)c1[i]);
                stA += v0; stA2 += v0 * v0;
                stB += v1; stB2 += v1 * v1;
            }
        }
#pragma unroll
        for (int h = 0; h < 2; h++) {
            const int kc = h ? kc1 : kc0;
            bf16x8 af[2], bfr[4];
#pragma unroll
            for (int mi = 0; mi < 2; mi++)
                af[mi] = __builtin_bit_cast(bf16x8,
                    *(const short8*)&lsA[(wr + mi * 16 + mrow) * 64 + kc]);
#pragma unroll
            for (int ni = 0; ni < 4; ni++)
                bfr[ni] = __builtin_bit_cast(bf16x8,
                    *(const short8*)&lsB[(wc + ni * 16 + mrow) * 64 + kc]);
#pragma unroll
            for (int mi = 0; mi < 2; mi++)
#pragma unroll
                for (int ni = 0; ni < 4; ni++)
                    acc[mi][ni] = __builtin_amdgcn_mfma_f32_16x16x32_bf16(
                        af[mi], bfr[ni], acc[mi][ni], 0, 0, 0);
        }
        __syncthreads();
    }

    if (MODE == 5) {
        // fused qkv epilogue: Xb (scalar), XT (u16x4: 4 consecutive rows =
        // 4 consecutive n at fixed col), per-row sum(exp) -> atomicAdd.
        u16* XT = const_cast<u16*>(Xres);
        float2* sm = const_cast<float2*>(stats);
        float rsum[2][4] = {{0.f,0.f,0.f,0.f},{0.f,0.f,0.f,0.f}};
#pragma unroll
        for (int mi = 0; mi < 2; mi++) {
#pragma unroll
            for (int ni = 0; ni < 4; ni++) {
                const int col  = colBase + wc + ni * 16 + mrow;
                const int row0 = rowBase + wr + mi * 16 + q * 4;
                u16x4 hv;
#pragma unroll
                for (int r = 0; r < 4; r++) {
                    const u16 h = f2b(acc[mi][ni][r]);
                    hv[r] = h;
                    outB[(size_t)(row0 + r) * ldo + col] = h;
                    rsum[mi][r] += __expf(b2f(h));
                }
                *(u16x4*)(XT + (size_t)(row0 >> 12) * 1048576
                             + (size_t)col * 4096 + (row0 & 4095)) = hv;
            }
        }
#pragma unroll
        for (int mi = 0; mi < 2; mi++)
#pragma unroll
            for (int r = 0; r < 4; r++) {
                float s = rsum[mi][r];
                s += __shfl_xor(s, 1); s += __shfl_xor(s, 2);
                s += __shfl_xor(s, 4); s += __shfl_xor(s, 8);
                if (mrow == 0)
                    atomicAdd(&sm[rowBase + wr + mi * 16 + q * 4 + r].y, s);
            }
        return;
    }

    if (MODE == 4) {
        // finish in-kernel LN1024 stats: reduce over 8 chunk-threads/row
        for (int o = 1; o <= 4; o <<= 1) {
            stA  += __shfl_xor(stA,  o);  stA2 += __shfl_xor(stA2, o);
            stB  += __shfl_xor(stB,  o);  stB2 += __shfl_xor(stB2, o);
        }
        if ((lane & 7) == 0) {
            lstat[sRow]      = make_float2(stA, stA2);
            lstat[sRow + 64] = make_float2(stB, stB2);
        }
        __syncthreads();
        float mean_[2][4], rstd_[2][4];
#pragma unroll
        for (int mi = 0; mi < 2; mi++)
#pragma unroll
            for (int r = 0; r < 4; r++) {
                const float2 s = lstat[wr + mi * 16 + q * 4 + r];
                const float mean = s.x * (1.f / 1024.f);
                const float var  = s.y * (1.f / 1024.f) - mean * mean;
                mean_[mi][r] = mean;
                rstd_[mi][r] = rsqrtf(var + 1e-5f);
            }
#pragma unroll
        for (int mi = 0; mi < 2; mi++) {
#pragma unroll
            for (int ni = 0; ni < 4; ni++) {
                const int col = colBase + wc + ni * 16 + mrow;
#pragma unroll
                for (int r = 0; r < 4; r++) {
                    const int row = rowBase + wr + mi * 16 + q * 4 + r;
                    float v = acc[mi][ni][r];
                    v = rstd_[mi][r] * (v - mean_[mi][r] * g[col]) + be[col]
                        + 2.f * b2f(Xres[(size_t)row * 256 + col]);
                    outB[(size_t)row * ldo + col] = f2b(v);
                }
            }
        }
        return;
    }

    // epilogue: lane holds D[row = q*4+r][col = mrow] per 16x16 tile
#pragma unroll
    for (int mi = 0; mi < 2; mi++) {
#pragma unroll
        for (int ni = 0; ni < 4; ni++) {
            const int col = colBase + wc + ni * 16 + mrow;
#pragma unroll
            for (int r = 0; r < 4; r++) {
                const int row = rowBase + wr + mi * 16 + q * 4 + r;
                float v = acc[mi][ni][r];
                if (MODE == 0) {
                    outB[(size_t)batch * sOB + (size_t)row * ldo + col] = f2b(v);
                } else if (MODE == 1) {
                    // bf16 split-K partial for slice (batch, ks)
                    outB[((size_t)batch * nKsplit + ks) * sOB
                         + (size_t)row * ldo + col] = f2b(v);
                } else if (MODE == 3) {
                    v += bias[col];
                    v = v > 0.f ? v : 0.f;
                    outB[(size_t)row * ldo + col] = f2b(v);
                }
            }
        }
    }
}

// ---------------------------------------------------------------------------
// Transpose (R x Cc) -> (Cc x R) per batch, with dtype conversion.
// ---------------------------------------------------------------------------
template<typename TIN, typename TOUT>
__global__ __launch_bounds__(256)
void transpose_k(const TIN* __restrict__ in, TOUT* __restrict__ out,
                 int R, int Cc, long sIn, long sOut)
{
    __shared__ TOUT tile[32][33];
    const int b = blockIdx.z;
    const TIN* ib = in + (size_t)b * sIn;
    TOUT* ob = out + (size_t)b * sOut;
    const int c0 = blockIdx.x * 32, r0 = blockIdx.y * 32;
    const int tx = threadIdx.x & 31, ty = threadIdx.x >> 5;
#pragma unroll
    for (int i = 0; i < 32; i += 8)
        cvt(ib[(size_t)(r0 + ty + i) * Cc + c0 + tx], tile[ty + i][tx]);
    __syncthreads();
#pragma unroll
    for (int i = 0; i < 32; i += 8)
        ob[(size_t)(c0 + ty + i) * R + r0 + tx] = tile[tx][ty + i];
}

// ---------------------------------------------------------------------------
// Fused LN256 + transpose (unchanged from r5).
// ---------------------------------------------------------------------------
template<typename OUTT, bool WRITE_VB>
__global__ __launch_bounds__(256)
void ln256t_k(const u16* __restrict__ Tb, const float* __restrict__ g,
              const float* __restrict__ be, u16* __restrict__ Vb,
              OUTT* __restrict__ outT)
{
    constexpr int STRIDE = (sizeof(OUTT) == 2) ? 266 : 261;
    __shared__ OUTT tile[32 * STRIDE];
    const int wid = threadIdx.x >> 6, lane = threadIdx.x & 63;
    const int bx = blockIdx.x;
    const size_t r0 = (size_t)bx * 32;
    const int b  = bx >> 7;
    const int n0 = (bx & 127) * 32;

#pragma unroll
    for (int j = 0; j < 8; j++) {
        const int lr = wid * 8 + j;
        const size_t row = r0 + lr;
        const u16x4 tb = *(const u16x4*)(Tb + row * 256 + lane * 4);
        const float x0 = b2f(tb.x), x1 = b2f(tb.y), x2 = b2f(tb.z), x3 = b2f(tb.w);
        float s  = x0 + x1 + x2 + x3;
        float s2 = x0 * x0 + x1 * x1 + x2 * x2 + x3 * x3;
        for (int o = 32; o > 0; o >>= 1) { s += __shfl_xor(s, o); s2 += __shfl_xor(s2, o); }
        const float mean = s * (1.f / 256.f);
        const float var  = s2 * (1.f / 256.f) - mean * mean;
        const float rstd = rsqrtf(var + 1e-5f);
        const int c = lane * 4;
        float4 ov = { (x0 - mean) * rstd * g[c + 0] + be[c + 0],
                      (x1 - mean) * rstd * g[c + 1] + be[c + 1],
                      (x2 - mean) * rstd * g[c + 2] + be[c + 2],
                      (x3 - mean) * rstd * g[c + 3] + be[c + 3] };
        if (WRITE_VB) {
            u16x4 vb = { f2b(ov.x), f2b(ov.y), f2b(ov.z), f2b(ov.w) };
            *(u16x4*)(Vb + row * 256 + c) = vb;
        }
        OUTT* tl = &tile[lr * STRIDE + c];
        cvt(ov.x, tl[0]); cvt(ov.y, tl[1]); cvt(ov.z, tl[2]); cvt(ov.w, tl[3]);
    }
    __syncthreads();

    const int c = threadIdx.x;
    OUTT* dst = outT + ((size_t)b * 256 + c) * 4096 + n0;
    if (sizeof(OUTT) == 2) {
#pragma unroll
        for (int k = 0; k < 4; k++) {
            u16x8 v;
#pragma unroll
            for (int i = 0; i < 8; i++) v[i] = *(const u16*)&tile[(k * 8 + i) * STRIDE + c];
            *(u16x8*)((u16*)dst + k * 8) = v;
        }
    } else {
#pragma unroll
        for (int k = 0; k < 8; k++) {
            float4 v;
            v.x = *(const float*)&tile[(k * 4 + 0) * STRIDE + c];
            v.y = *(const float*)&tile[(k * 4 + 1) * STRIDE + c];
            v.z = *(const float*)&tile[(k * 4 + 2) * STRIDE + c];
            v.w = *(const float*)&tile[(k * 4 + 3) * STRIDE + c];
            *(float4*)((float*)dst + k * 4) = v;
        }
    }
}

// Reduce 16 bf16 split-K partial ctx buffers -> bf16 (fp32 accumulate).
__global__ __launch_bounds__(256)
void ctxreduce_k(const u16* __restrict__ ctxp, u16* __restrict__ ctxb)
{
    const int i = blockIdx.x * 256 + threadIdx.x;      // 131072 x u16x4 groups
    const int batch  = i >> 14;
    const int within = i & 16383;
    const u16x4* src = (const u16x4*)ctxp + (size_t)batch * 16 * 16384 + within;
    float4 s = {0.f, 0.f, 0.f, 0.f};
#pragma unroll
    for (int ks = 0; ks < 16; ks++) {
        const u16x4 v = src[(size_t)ks * 16384];
        s.x += b2f(v.x); s.y += b2f(v.y); s.z += b2f(v.z); s.w += b2f(v.w);
    }
    u16x4 o = { f2b(s.x), f2b(s.y), f2b(s.z), f2b(s.w) };
    ((u16x4*)ctxb)[i] = o;
}

// Convert Wqkv and Wmlp fp32->bf16 in one launch (Wres handled by wresprep_k).
__global__ __launch_bounds__(256)
void wconv_k(const float* __restrict__ Wq, const float* __restrict__ Wm,
             u16* __restrict__ oq, u16* __restrict__ om)
{
    const int i = blockIdx.x * 256 + threadIdx.x;
    const float* src; u16* dst; int j;
    if (i < 16384) { src = Wq; dst = oq; j = i; }
    else           { src = Wm; dst = om; j = i - 16384; }
    const float4 v = ((const float4*)src)[j];
    u16x4 o = { f2b(v.x), f2b(v.y), f2b(v.z), f2b(v.w) };
    ((u16x4*)dst)[j] = o;
}

// LN-fold prep: Wr_b[c,k] = bf16(Wres[c,k]*g1[k]);
// sg[c] = sum_k g1[k]*Wres[c,k];  br[c] = sum_k be1[k]*Wres[c,k].
// Also zeroes smst (32768 float2): thread i zeroes smst[2i], smst[2i+1].
__global__ __launch_bounds__(256)
void wresprep_k(const float* __restrict__ Wres, const float* __restrict__ g1,
                const float* __restrict__ be1, u16* __restrict__ Wr_b,
                float* __restrict__ sg, float* __restrict__ br,
                float2* __restrict__ smst)
{
    const int tid = blockIdx.x * 256 + threadIdx.x;    // 0..16383
    smst[tid * 2]     = make_float2(0.f, 0.f);
    smst[tid * 2 + 1] = make_float2(0.f, 0.f);

    const int wv = threadIdx.x >> 6, lane = threadIdx.x & 63;
    const int row = blockIdx.x * 4 + wv;
    const float* src = Wres + (size_t)row * 1024;
    float s = 0.f, b = 0.f;
#pragma unroll
    for (int j = 0; j < 4; j++) {
        const int c = j * 256 + lane * 4;
        const float4 w  = *(const float4*)(src + c);
        const float4 gg = *(const float4*)(g1 + c);
        const float4 bb = *(const float4*)(be1 + c);
        const float4 wg = { w.x * gg.x, w.y * gg.y, w.z * gg.z, w.w * gg.w };
        u16x4 o = { f2b(wg.x), f2b(wg.y), f2b(wg.z), f2b(wg.w) };
        *(u16x4*)(Wr_b + (size_t)row * 1024 + c) = o;
        s += wg.x + wg.y + wg.z + wg.w;
        b += w.x * bb.x + w.y * bb.y + w.z * bb.z + w.w * bb.w;
    }
    for (int o = 32; o > 0; o >>= 1) { s += __shfl_xor(s, o); b += __shfl_xor(b, o); }
    if (lane == 0) { sg[row] = s; br[row] = b; }
}

extern "C" void kernel_launch(void* const* d_in, const int* in_sizes, int n_in,
                              void* d_out, int out_size, void* d_ws, size_t ws_size,
                              hipStream_t stream)
{
    (void)in_sizes; (void)n_in; (void)out_size; (void)ws_size;
    const float* x    = (const float*)d_in[0];
    const float* Wqkv = (const float*)d_in[1];
    const float* Wmlp = (const float*)d_in[2];
    const float* bmlp = (const float*)d_in[3];
    const float* g1   = (const float*)d_in[4];
    const float* be1  = (const float*)d_in[5];
    const float* Wres = (const float*)d_in[6];
    const float* g2   = (const float*)d_in[7];
    const float* be2  = (const float*)d_in[8];

    // workspace (~156 MiB of 256)
    char* ws = (char*)d_ws;
    u16*    Xb   = (u16*)ws;    ws += (size_t)16777216;   // (32768,256)
    u16*    XT   = (u16*)ws;    ws += (size_t)16777216;   // (B,256,4096)
    u16*    Vb   = (u16*)ws;    ws += (size_t)16777216;   // (32768,256)
    u16*    VT2  = (u16*)ws;    ws += (size_t)16777216;   // (B,256,4096)
    u16*    OUT  = (u16*)ws;    ws += (size_t)16777216;   // (32768,256)
    u16*    MLPo = (u16*)ws;    ws += (size_t)33554432;   // (32768,512)
    u16*    Tb   = (u16*)ws;    ws += (size_t)16777216;   // (32768,256)
    u16*    ctxp = (u16*)ws;    ws += (size_t)16777216;   // (B*16,256,256) bf16
    u16*    ctxb = (u16*)ws;    ws += (size_t)1048576;    // (B,256,256)
    float2* smst = (float2*)ws; ws += (size_t)262144;     // (32768) {0,sumexp}
    u16*    Wq_b = (u16*)ws;    ws += (size_t)131072;
    u16*    Wm_b = (u16*)ws;    ws += (size_t)524288;
    u16*    Wr_b = (u16*)ws;    ws += (size_t)524288;
    float*  sg   = (float*)ws;  ws += (size_t)1024;       // (256) sum g*Wres
    float*  br   = (float*)ws;  ws += (size_t)1024;       // (256) sum be*Wres
    u16*    xt   = MLPo;  // alias: xt dead before MLPo's first write

    // 0. weights fp32 -> bf16 (+ LN-fold prep for Wres, zeroes smst)
    wconv_k<<<dim3(320), 256, 0, stream>>>(Wqkv, Wmlp, Wq_b, Wm_b);
    wresprep_k<<<dim3(64), 256, 0, stream>>>(Wres, g1, be1, Wr_b, sg, br, smst);

    // 1. xt = transpose(x): per batch (256,4096) fp32 -> (4096,256) bf16
    transpose_k<float, u16><<<dim3(128, 8, 8), 256, 0, stream>>>(
        x, xt, 256, 4096, 256L * 4096, 4096L * 256);

    // 2. fused qkv: Xb = xt @ Wqkv^T, XT = Xb^T (per batch), smst.y = rowsum
    //    of exp(Xb)  [M=32768,N=256,K=256]
    gemm_bt<5, 0><<<dim3(2, 256, 1), 512, 0, stream>>>(
        xt, nullptr, nullptr, 256, 0, 0, 0, Wq_b, 256, 0, 0, 0, 256, 1,
        nullptr, Xb, 0, 0, 256, XT, nullptr, smst, nullptr, nullptr);

    const u16* VTcur = XT;
    const u16* Vcur  = Xb;

    for (int it = 0; it < 2; ++it) {
        // ctx split-K=16 bf16 partials
        gemm_bt<1, 0><<<dim3(2, 2, 128), 512, 0, stream>>>(
            VTcur, nullptr, nullptr, 4096, 0, 0, 0, XT, 4096,
            1048576, 1048576, 0, 256, 16,
            nullptr, ctxp, 0, 65536, 256, nullptr, nullptr, nullptr, nullptr, nullptr);
        ctxreduce_k<<<dim3(512), 256, 0, stream>>>(ctxp, ctxb);

        // OUT = softmax(Xb) @ ctxT^T  (exp in staging) [per batch 4096x256,K=256]
        gemm_bt<0, 1><<<dim3(2, 32, 8), 512, 0, stream>>>(
            Xb, nullptr, nullptr, 256, 0, 0, 0, ctxb, 256,
            1048576, 65536, 4096, 256, 1,
            nullptr, OUT, 0, 1048576, 256, nullptr, nullptr, smst, nullptr, nullptr);

        // MLPo = relu([OUT|Vcur] @ Wmlp^T + b)  [M=32768,N=512,K=512 split@256]
        gemm_bt<3, 3><<<dim3(4, 256, 1), 512, 0, stream>>>(
            OUT, Vcur, nullptr, 256, 256, 0, 256, Wm_b, 512, 0, 0, 0, 512, 1,
            nullptr, MLPo, 0, 0, 512, nullptr, bmlp, nullptr, nullptr, nullptr);

        // Tb = LN1024([OUT|Vcur|MLPo]) @ Wres^T + 2*Xb  [M=32768,N=256,K=1024]
        // LN stats computed IN-KERNEL from staged A tiles (stats1024 deleted);
        // LN folded into Wr_b/sg/br; applied in the epilogue.
        gemm_bt<4, 2><<<dim3(2, 256, 1), 512, 0, stream>>>(
            OUT, Vcur, MLPo, 256, 256, 512, 0, Wr_b, 1024, 0, 0, 0, 1024, 1,
            nullptr, Tb, 0, 0, 256, Xb, nullptr, nullptr, sg, br);

        // LN256 + transpose fused
        if (it == 0) {
            ln256t_k<u16, true><<<dim3(1024), 256, 0, stream>>>(
                Tb, g2, be2, Vb, VT2);
            VTcur = VT2;
            Vcur  = Vb;
        } else {
            ln256t_k<float, false><<<dim3(1024), 256, 0, stream>>>(
                Tb, g2, be2, nullptr, (float*)d_out);
        }
    }
}